// Round 1
// baseline (984.665 us; speedup 1.0000x reference)
//
#include <hip/hip_runtime.h>
#include <math.h>

// Problem constants
#define B_ 16
#define L_ 1024
#define D_ 768

// GEMM tile config: 64x64 output tile, 256 threads, 4x4 micro-tile, BK=16
#define BM 64
#define BN 64
#define BK 16
#define LDSP 68   // padded leading dim (floats), stride 272B = 17*16B (16B aligned, conflict-light)

// ---------------------------------------------------------------------------
// K0: canonicalize mask. Harness dtype for a jax bool array is ambiguous
// (bool bytes vs int32 vs int64). Detect on device, write int[16384], 1=pad.
// ---------------------------------------------------------------------------
__global__ __launch_bounds__(256) void k_mask(const void* __restrict__ mraw,
                                              int* __restrict__ canon) {
  __shared__ int flags[2];  // [0]=any int32 word >1 (=> byte-packed bools)
                            // [1]=any odd int32 word nonzero (=> NOT int64)
  if (threadIdx.x < 2) flags[threadIdx.x] = 0;
  __syncthreads();
  const unsigned* m32 = (const unsigned*)mraw;
  int gt = 0, oddnz = 0;
  for (int i = threadIdx.x; i < 4096; i += 256) {  // 16KB scan: safe for all layouts
    unsigned v = m32[i];
    if (v > 1u) gt = 1;
    if ((i & 1) && v != 0u) oddnz = 1;
  }
  if (gt) atomicOr(&flags[0], 1);
  if (oddnz) atomicOr(&flags[1], 1);
  __syncthreads();
  const int mode = flags[0] ? 0 : (flags[1] ? 1 : 2);  // 0=u8, 1=i32, 2=i64
  for (int i = threadIdx.x; i < B_ * L_; i += 256) {
    int v;
    if (mode == 0)      v = ((const unsigned char*)mraw)[i];
    else if (mode == 1) v = ((const int*)mraw)[i];
    else                v = (int)(((const long long*)mraw)[i] != 0);
    canon[i] = (v != 0);
  }
}

// ---------------------------------------------------------------------------
// K1: P[m][n] = relu( sum_k X[m][k]*W[n][k] + bias[n] ),  M=16384, N=K=768
// ---------------------------------------------------------------------------
__global__ __launch_bounds__(256) void k_proj(const float* __restrict__ X,
                                              const float* __restrict__ W,
                                              const float* __restrict__ bias,
                                              float* __restrict__ P) {
  __shared__ float As[BK][LDSP];
  __shared__ float Bs[BK][LDSP];
  const int tid = threadIdx.x;
  const int m0 = blockIdx.y * BM;
  const int n0 = blockIdx.x * BN;
  const int tm = tid >> 4, tn = tid & 15;
  const int lr = tid >> 2;   // 0..63 row of tile
  const int lq = tid & 3;    // float4 index within 16-wide k chunk
  const float* Arow = X + (size_t)(m0 + lr) * D_ + lq * 4;
  const float* Brow = W + (size_t)(n0 + lr) * D_ + lq * 4;
  float acc[4][4] = {};
  for (int k0 = 0; k0 < D_; k0 += BK) {
    const float4 a = *(const float4*)(Arow + k0);
    const float4 b = *(const float4*)(Brow + k0);
    __syncthreads();
    As[lq * 4 + 0][lr] = a.x; As[lq * 4 + 1][lr] = a.y;
    As[lq * 4 + 2][lr] = a.z; As[lq * 4 + 3][lr] = a.w;
    Bs[lq * 4 + 0][lr] = b.x; Bs[lq * 4 + 1][lr] = b.y;
    Bs[lq * 4 + 2][lr] = b.z; Bs[lq * 4 + 3][lr] = b.w;
    __syncthreads();
#pragma unroll
    for (int k = 0; k < BK; ++k) {
      const float4 av = *(const float4*)&As[k][tm * 4];
      const float4 bv = *(const float4*)&Bs[k][tn * 4];
      const float ar[4] = {av.x, av.y, av.z, av.w};
      const float br[4] = {bv.x, bv.y, bv.z, bv.w};
#pragma unroll
      for (int i = 0; i < 4; ++i)
#pragma unroll
        for (int j = 0; j < 4; ++j) acc[i][j] += ar[i] * br[j];
    }
  }
  const float4 bb = *(const float4*)(bias + n0 + tn * 4);
#pragma unroll
  for (int i = 0; i < 4; ++i) {
    float4 o;
    o.x = fmaxf(acc[i][0] + bb.x, 0.f);
    o.y = fmaxf(acc[i][1] + bb.y, 0.f);
    o.z = fmaxf(acc[i][2] + bb.z, 0.f);
    o.w = fmaxf(acc[i][3] + bb.w, 0.f);
    *(float4*)(P + (size_t)(m0 + tm * 4 + i) * D_ + n0 + tn * 4) = o;
  }
}

// ---------------------------------------------------------------------------
// K2: per batch: S[l][m] = dot(P[b,l,:], P[b,m,:]); diag->0; masked col->-inf
// ---------------------------------------------------------------------------
__global__ __launch_bounds__(256) void k_scores(const float* __restrict__ P,
                                                const int* __restrict__ mask,
                                                float* __restrict__ S) {
  __shared__ float As[BK][LDSP];
  __shared__ float Bs[BK][LDSP];
  const int tid = threadIdx.x;
  const int bb = blockIdx.z;
  const int l0 = blockIdx.y * BM;
  const int m0 = blockIdx.x * BN;
  const int tm = tid >> 4, tn = tid & 15;
  const int lr = tid >> 2;
  const int lq = tid & 3;
  const float* Arow = P + ((size_t)(bb * L_ + l0 + lr)) * D_ + lq * 4;
  const float* Brow = P + ((size_t)(bb * L_ + m0 + lr)) * D_ + lq * 4;
  float acc[4][4] = {};
  for (int k0 = 0; k0 < D_; k0 += BK) {
    const float4 a = *(const float4*)(Arow + k0);
    const float4 b = *(const float4*)(Brow + k0);
    __syncthreads();
    As[lq * 4 + 0][lr] = a.x; As[lq * 4 + 1][lr] = a.y;
    As[lq * 4 + 2][lr] = a.z; As[lq * 4 + 3][lr] = a.w;
    Bs[lq * 4 + 0][lr] = b.x; Bs[lq * 4 + 1][lr] = b.y;
    Bs[lq * 4 + 2][lr] = b.z; Bs[lq * 4 + 3][lr] = b.w;
    __syncthreads();
#pragma unroll
    for (int k = 0; k < BK; ++k) {
      const float4 av = *(const float4*)&As[k][tm * 4];
      const float4 bv = *(const float4*)&Bs[k][tn * 4];
      const float ar[4] = {av.x, av.y, av.z, av.w};
      const float br[4] = {bv.x, bv.y, bv.z, bv.w};
#pragma unroll
      for (int i = 0; i < 4; ++i)
#pragma unroll
        for (int j = 0; j < 4; ++j) acc[i][j] += ar[i] * br[j];
    }
  }
  int mcol[4];
#pragma unroll
  for (int j = 0; j < 4; ++j) mcol[j] = mask[bb * L_ + m0 + tn * 4 + j];
#pragma unroll
  for (int i = 0; i < 4; ++i) {
    const int l = l0 + tm * 4 + i;
    float4 o;
    float* op = (float*)&o;
#pragma unroll
    for (int j = 0; j < 4; ++j) {
      const int m = m0 + tn * 4 + j;
      float v = acc[i][j];
      if (m == l) v = 0.f;              // diag zeroed BEFORE mask (ref order)
      if (mcol[j]) v = -INFINITY;       // masked key column
      op[j] = v;
    }
    *(float4*)(S + ((size_t)(bb * L_ + l)) * L_ + m0 + tn * 4) = o;
  }
}

// ---------------------------------------------------------------------------
// K3: in-place row softmax over 1024 keys. exp(-inf - max) = 0 naturally.
// ---------------------------------------------------------------------------
__global__ __launch_bounds__(256) void k_softmax(float* __restrict__ S) {
  const size_t row = blockIdx.x;
  float4* rp = (float4*)(S + row * L_);
  float4 v = rp[threadIdx.x];
  float mx = fmaxf(fmaxf(v.x, v.y), fmaxf(v.z, v.w));
#pragma unroll
  for (int o = 32; o > 0; o >>= 1) mx = fmaxf(mx, __shfl_xor(mx, o));
  __shared__ float rmax[4], rsum[4];
  const int wv = threadIdx.x >> 6, ln = threadIdx.x & 63;
  if (ln == 0) rmax[wv] = mx;
  __syncthreads();
  mx = fmaxf(fmaxf(rmax[0], rmax[1]), fmaxf(rmax[2], rmax[3]));
  float4 e;
  e.x = __expf(v.x - mx); e.y = __expf(v.y - mx);
  e.z = __expf(v.z - mx); e.w = __expf(v.w - mx);
  float s = (e.x + e.y) + (e.z + e.w);
#pragma unroll
  for (int o = 32; o > 0; o >>= 1) s += __shfl_xor(s, o);
  if (ln == 0) rsum[wv] = s;
  __syncthreads();
  s = (rsum[0] + rsum[1]) + (rsum[2] + rsum[3]);
  const float inv = 1.0f / s;
  e.x *= inv; e.y *= inv; e.z *= inv; e.w *= inv;
  rp[threadIdx.x] = e;
}

// ---------------------------------------------------------------------------
// K4: per batch: align[l][d] = sum_m alpha[l][m] * X[b,m,d]
// ---------------------------------------------------------------------------
__global__ __launch_bounds__(256) void k_align(const float* __restrict__ A,
                                               const float* __restrict__ X,
                                               float* __restrict__ O) {
  __shared__ float As[BK][LDSP];
  __shared__ float Bs[BK][LDSP];
  const int tid = threadIdx.x;
  const int bb = blockIdx.z;
  const int l0 = blockIdx.y * BM;
  const int n0 = blockIdx.x * BN;
  const int tm = tid >> 4, tn = tid & 15;
  const int lr = tid >> 2;
  const int lq = tid & 3;
  const int kk = tid >> 4;   // 0..15 (B-tile row)
  const int nq = tid & 15;   // 0..15 (B-tile float4 col)
  const float* Arow = A + ((size_t)(bb * L_ + l0 + lr)) * L_ + lq * 4;
  float acc[4][4] = {};
  for (int k0 = 0; k0 < L_; k0 += BK) {
    const float4 a = *(const float4*)(Arow + k0);
    const float4 b = *(const float4*)(X + ((size_t)(bb * L_ + k0 + kk)) * D_ + n0 + nq * 4);
    __syncthreads();
    As[lq * 4 + 0][lr] = a.x; As[lq * 4 + 1][lr] = a.y;
    As[lq * 4 + 2][lr] = a.z; As[lq * 4 + 3][lr] = a.w;
    *(float4*)&Bs[kk][nq * 4] = b;
    __syncthreads();
#pragma unroll
    for (int k = 0; k < BK; ++k) {
      const float4 av = *(const float4*)&As[k][tm * 4];
      const float4 bv = *(const float4*)&Bs[k][tn * 4];
      const float ar[4] = {av.x, av.y, av.z, av.w};
      const float br[4] = {bv.x, bv.y, bv.z, bv.w};
#pragma unroll
      for (int i = 0; i < 4; ++i)
#pragma unroll
        for (int j = 0; j < 4; ++j) acc[i][j] += ar[i] * br[j];
    }
  }
#pragma unroll
  for (int i = 0; i < 4; ++i) {
    float4 o;
    o.x = acc[i][0]; o.y = acc[i][1]; o.z = acc[i][2]; o.w = acc[i][3];
    *(float4*)(O + ((size_t)(bb * L_ + l0 + tm * 4 + i)) * D_ + n0 + tn * 4) = o;
  }
}

// ---------------------------------------------------------------------------
extern "C" void kernel_launch(void* const* d_in, const int* in_sizes, int n_in,
                              void* d_out, int out_size, void* d_ws, size_t ws_size,
                              hipStream_t stream) {
  const float* X    = (const float*)d_in[0];  // [B,L,D]
  const void*  mraw = d_in[1];                // [B,L] bool/int
  const float* W    = (const float*)d_in[2];  // [D,D]
  const float* bias = (const float*)d_in[3];  // [D]

  float* out   = (float*)d_out;
  float* align = out;                          // B*L*D
  float* alpha = out + (size_t)B_ * L_ * D_;   // B*L*L
  int*   maskC = (int*)d_ws;                   // 64KB
  // P (f32 [B*L, D]) reuses the align region: it is dead before k_align writes.
  float* P = align;

  hipLaunchKernelGGL(k_mask, dim3(1), dim3(256), 0, stream, mraw, maskC);
  hipLaunchKernelGGL(k_proj, dim3(D_ / BN, (B_ * L_) / BM), dim3(256), 0, stream,
                     X, W, bias, P);
  hipLaunchKernelGGL(k_scores, dim3(L_ / BN, L_ / BM, B_), dim3(256), 0, stream,
                     P, maskC, alpha);
  hipLaunchKernelGGL(k_softmax, dim3(B_ * L_), dim3(256), 0, stream, alpha);
  hipLaunchKernelGGL(k_align, dim3(D_ / BN, L_ / BM, B_), dim3(256), 0, stream,
                     alpha, X, align);
}

// Round 2
// 530.356 us; speedup vs baseline: 1.8566x; 1.8566x over previous
//
#include <hip/hip_runtime.h>
#include <math.h>

// Problem constants
#define B_ 16
#define L_ 1024
#define D_ 768

typedef short bf16x8 __attribute__((ext_vector_type(8)));
typedef float f32x4 __attribute__((ext_vector_type(4)));

// round-to-nearest-even f32 -> bf16 (bit trick; inputs never NaN)
__device__ __forceinline__ unsigned short f2bf(float x) {
  unsigned u = __float_as_uint(x);
  u = (u + 0x7FFFu + ((u >> 16) & 1u)) >> 16;
  return (unsigned short)u;
}
__device__ __forceinline__ float bf2f(unsigned short h) {
  return __uint_as_float(((unsigned)h) << 16);
}

// ---------------------------------------------------------------------------
// K0: canonicalize mask (bool-bytes / int32 / int64 auto-detect). 1 = padding.
// ---------------------------------------------------------------------------
__global__ __launch_bounds__(256) void k_mask(const void* __restrict__ mraw,
                                              int* __restrict__ canon) {
  __shared__ int flags[2];
  if (threadIdx.x < 2) flags[threadIdx.x] = 0;
  __syncthreads();
  const unsigned* m32 = (const unsigned*)mraw;
  int gt = 0, oddnz = 0;
  for (int i = threadIdx.x; i < 4096; i += 256) {
    unsigned v = m32[i];
    if (v > 1u) gt = 1;
    if ((i & 1) && v != 0u) oddnz = 1;
  }
  if (gt) atomicOr(&flags[0], 1);
  if (oddnz) atomicOr(&flags[1], 1);
  __syncthreads();
  const int mode = flags[0] ? 0 : (flags[1] ? 1 : 2);  // 0=u8, 1=i32, 2=i64
  for (int i = threadIdx.x; i < B_ * L_; i += 256) {
    int v;
    if (mode == 0)      v = ((const unsigned char*)mraw)[i];
    else if (mode == 1) v = ((const int*)mraw)[i];
    else                v = (int)(((const long long*)mraw)[i] != 0);
    canon[i] = (v != 0);
  }
}

// ---------------------------------------------------------------------------
// K1 (MFMA): P = relu(X·W^T + b), split to bf16 hi/lo pair (Ph, Pl).
// fp32 inputs are hi/lo-split on the fly in staging; 3 MFMA passes (hh+hl+lh).
// 128x128 tile, 4 waves (2x2), wave = 64x64 = 4x4 frags of 16x16x32, BK=32.
// ---------------------------------------------------------------------------
__global__ __launch_bounds__(256) void k_proj(const float* __restrict__ X,
                                              const float* __restrict__ W,
                                              const float* __restrict__ bias,
                                              unsigned short* __restrict__ Ph,
                                              unsigned short* __restrict__ Pl) {
  __shared__ unsigned short Ah[128][32], Al[128][32], Bh[128][32], Bl[128][32];
  const int tid = threadIdx.x;
  const int m0 = blockIdx.y * 128, n0 = blockIdx.x * 128;
  const int lane = tid & 63;
  const int wr = (tid >> 7) & 1, wc = (tid >> 6) & 1;
  const int fr = lane & 15, kg = lane >> 4;
  f32x4 acc[4][4];
#pragma unroll
  for (int i = 0; i < 4; ++i)
#pragma unroll
    for (int j = 0; j < 4; ++j) acc[i][j] = 0;

  for (int kk = 0; kk < D_; kk += 32) {
    float4 av[4], bv[4];
#pragma unroll
    for (int p = 0; p < 4; ++p) {
      const int f = tid + p * 256;
      const int r = f >> 3, c = f & 7;
      av[p] = *(const float4*)(X + (size_t)(m0 + r) * D_ + kk + c * 4);
      bv[p] = *(const float4*)(W + (size_t)(n0 + r) * D_ + kk + c * 4);
    }
    __syncthreads();
#pragma unroll
    for (int p = 0; p < 4; ++p) {
      const int f = tid + p * 256;
      const int r = f >> 3, c = f & 7;
      {
        const float x0 = av[p].x, x1 = av[p].y, x2 = av[p].z, x3 = av[p].w;
        const unsigned short h0 = f2bf(x0), h1 = f2bf(x1), h2 = f2bf(x2), h3 = f2bf(x3);
        *(ushort4*)&Ah[r][c * 4] = make_ushort4(h0, h1, h2, h3);
        *(ushort4*)&Al[r][c * 4] = make_ushort4(f2bf(x0 - bf2f(h0)), f2bf(x1 - bf2f(h1)),
                                                f2bf(x2 - bf2f(h2)), f2bf(x3 - bf2f(h3)));
      }
      {
        const float x0 = bv[p].x, x1 = bv[p].y, x2 = bv[p].z, x3 = bv[p].w;
        const unsigned short h0 = f2bf(x0), h1 = f2bf(x1), h2 = f2bf(x2), h3 = f2bf(x3);
        *(ushort4*)&Bh[r][c * 4] = make_ushort4(h0, h1, h2, h3);
        *(ushort4*)&Bl[r][c * 4] = make_ushort4(f2bf(x0 - bf2f(h0)), f2bf(x1 - bf2f(h1)),
                                                f2bf(x2 - bf2f(h2)), f2bf(x3 - bf2f(h3)));
      }
    }
    __syncthreads();
    bf16x8 fah[4], fal[4], fbh[4], fbl[4];
#pragma unroll
    for (int i = 0; i < 4; ++i) {
      fah[i] = *(const bf16x8*)&Ah[wr * 64 + i * 16 + fr][kg * 8];
      fal[i] = *(const bf16x8*)&Al[wr * 64 + i * 16 + fr][kg * 8];
      fbh[i] = *(const bf16x8*)&Bh[wc * 64 + i * 16 + fr][kg * 8];
      fbl[i] = *(const bf16x8*)&Bl[wc * 64 + i * 16 + fr][kg * 8];
    }
#pragma unroll
    for (int i = 0; i < 4; ++i)
#pragma unroll
      for (int j = 0; j < 4; ++j) {
        acc[i][j] = __builtin_amdgcn_mfma_f32_16x16x32_bf16(fah[i], fbh[j], acc[i][j], 0, 0, 0);
        acc[i][j] = __builtin_amdgcn_mfma_f32_16x16x32_bf16(fah[i], fbl[j], acc[i][j], 0, 0, 0);
        acc[i][j] = __builtin_amdgcn_mfma_f32_16x16x32_bf16(fal[i], fbh[j], acc[i][j], 0, 0, 0);
      }
  }
#pragma unroll
  for (int j = 0; j < 4; ++j) {
    const int gc = n0 + wc * 64 + j * 16 + fr;
    const float bb = bias[gc];
#pragma unroll
    for (int i = 0; i < 4; ++i) {
      const int gr0 = m0 + wr * 64 + i * 16 + kg * 4;
#pragma unroll
      for (int r = 0; r < 4; ++r) {
        float v = fmaxf(acc[i][j][r] + bb, 0.f);
        const unsigned short h = f2bf(v);
        Ph[(size_t)(gr0 + r) * D_ + gc] = h;
        Pl[(size_t)(gr0 + r) * D_ + gc] = f2bf(v - bf2f(h));
      }
    }
  }
}

// ---------------------------------------------------------------------------
// K2 (MFMA): S = P·P^T per batch from pre-split (Ph, Pl); diag->0, mask->-inf.
// ---------------------------------------------------------------------------
__global__ __launch_bounds__(256) void k_scores(const unsigned short* __restrict__ Ph,
                                                const unsigned short* __restrict__ Pl,
                                                const int* __restrict__ mask,
                                                float* __restrict__ S) {
  __shared__ unsigned short Ah[128][32], Al[128][32], Bh[128][32], Bl[128][32];
  const int tid = threadIdx.x;
  const int bb = blockIdx.z;
  const int l0 = blockIdx.y * 128, m0 = blockIdx.x * 128;
  const int lane = tid & 63;
  const int wr = (tid >> 7) & 1, wc = (tid >> 6) & 1;
  const int fr = lane & 15, kg = lane >> 4;
  f32x4 acc[4][4];
#pragma unroll
  for (int i = 0; i < 4; ++i)
#pragma unroll
    for (int j = 0; j < 4; ++j) acc[i][j] = 0;

  for (int kk = 0; kk < D_; kk += 32) {
    uint4 va[2], vla[2], vb[2], vlb[2];
#pragma unroll
    for (int p = 0; p < 2; ++p) {
      const int f = tid + p * 256;
      const int r = f >> 2, sl = f & 3;
      const size_t arow = ((size_t)bb * L_ + l0 + r) * D_ + kk + sl * 8;
      const size_t brow = ((size_t)bb * L_ + m0 + r) * D_ + kk + sl * 8;
      va[p]  = *(const uint4*)(Ph + arow);
      vla[p] = *(const uint4*)(Pl + arow);
      vb[p]  = *(const uint4*)(Ph + brow);
      vlb[p] = *(const uint4*)(Pl + brow);
    }
    __syncthreads();
#pragma unroll
    for (int p = 0; p < 2; ++p) {
      const int f = tid + p * 256;
      const int r = f >> 2, sl = f & 3;
      *(uint4*)&Ah[r][sl * 8] = va[p];
      *(uint4*)&Al[r][sl * 8] = vla[p];
      *(uint4*)&Bh[r][sl * 8] = vb[p];
      *(uint4*)&Bl[r][sl * 8] = vlb[p];
    }
    __syncthreads();
    bf16x8 fah[4], fal[4], fbh[4], fbl[4];
#pragma unroll
    for (int i = 0; i < 4; ++i) {
      fah[i] = *(const bf16x8*)&Ah[wr * 64 + i * 16 + fr][kg * 8];
      fal[i] = *(const bf16x8*)&Al[wr * 64 + i * 16 + fr][kg * 8];
      fbh[i] = *(const bf16x8*)&Bh[wc * 64 + i * 16 + fr][kg * 8];
      fbl[i] = *(const bf16x8*)&Bl[wc * 64 + i * 16 + fr][kg * 8];
    }
#pragma unroll
    for (int i = 0; i < 4; ++i)
#pragma unroll
      for (int j = 0; j < 4; ++j) {
        acc[i][j] = __builtin_amdgcn_mfma_f32_16x16x32_bf16(fah[i], fbh[j], acc[i][j], 0, 0, 0);
        acc[i][j] = __builtin_amdgcn_mfma_f32_16x16x32_bf16(fah[i], fbl[j], acc[i][j], 0, 0, 0);
        acc[i][j] = __builtin_amdgcn_mfma_f32_16x16x32_bf16(fal[i], fbh[j], acc[i][j], 0, 0, 0);
      }
  }
#pragma unroll
  for (int j = 0; j < 4; ++j) {
    const int gm = m0 + wc * 64 + j * 16 + fr;
    const int mk = mask[bb * L_ + gm];
#pragma unroll
    for (int i = 0; i < 4; ++i) {
      const int gl0 = l0 + wr * 64 + i * 16 + kg * 4;
#pragma unroll
      for (int r = 0; r < 4; ++r) {
        const int gl = gl0 + r;
        float v = acc[i][j][r];
        if (gm == gl) v = 0.f;
        if (mk) v = -INFINITY;
        S[((size_t)bb * L_ + gl) * L_ + gm] = v;
      }
    }
  }
}

// ---------------------------------------------------------------------------
// K3: in-place row softmax over 1024 keys.
// ---------------------------------------------------------------------------
__global__ __launch_bounds__(256) void k_softmax(float* __restrict__ S) {
  const size_t row = blockIdx.x;
  float4* rp = (float4*)(S + row * L_);
  float4 v = rp[threadIdx.x];
  float mx = fmaxf(fmaxf(v.x, v.y), fmaxf(v.z, v.w));
#pragma unroll
  for (int o = 32; o > 0; o >>= 1) mx = fmaxf(mx, __shfl_xor(mx, o));
  __shared__ float rmax[4], rsum[4];
  const int wv = threadIdx.x >> 6, ln = threadIdx.x & 63;
  if (ln == 0) rmax[wv] = mx;
  __syncthreads();
  mx = fmaxf(fmaxf(rmax[0], rmax[1]), fmaxf(rmax[2], rmax[3]));
  float4 e;
  e.x = __expf(v.x - mx); e.y = __expf(v.y - mx);
  e.z = __expf(v.z - mx); e.w = __expf(v.w - mx);
  float s = (e.x + e.y) + (e.z + e.w);
#pragma unroll
  for (int o = 32; o > 0; o >>= 1) s += __shfl_xor(s, o);
  if (ln == 0) rsum[wv] = s;
  __syncthreads();
  s = (rsum[0] + rsum[1]) + (rsum[2] + rsum[3]);
  const float inv = 1.0f / s;
  e.x *= inv; e.y *= inv; e.z *= inv; e.w *= inv;
  rp[threadIdx.x] = e;
}

// ---------------------------------------------------------------------------
// K4: Xt[b][d][m] = bf16(X[b][m][d])  (so align GEMM is NT like the others)
// ---------------------------------------------------------------------------
__global__ __launch_bounds__(256) void k_transpose(const float* __restrict__ X,
                                                   unsigned short* __restrict__ Xt) {
  __shared__ float t[32][33];
  const int b = blockIdx.z;
  const int d0 = blockIdx.x * 32, m0 = blockIdx.y * 32;
  const int tx = threadIdx.x & 31, ty = threadIdx.x >> 5;
#pragma unroll
  for (int i = 0; i < 32; i += 8)
    t[ty + i][tx] = X[((size_t)b * L_ + m0 + ty + i) * D_ + d0 + tx];
  __syncthreads();
#pragma unroll
  for (int i = 0; i < 32; i += 8)
    Xt[((size_t)b * D_ + d0 + ty + i) * L_ + m0 + tx] = f2bf(t[tx][ty + i]);
}

// ---------------------------------------------------------------------------
// K5 (MFMA): align = alpha·X per batch.  A = alpha fp32 (-> bf16 in staging),
// B = Xt bf16 [d][m] (NT). Single bf16 pass (alpha in [0,1], X O(1)).
// ---------------------------------------------------------------------------
__global__ __launch_bounds__(256) void k_align(const float* __restrict__ A,
                                               const unsigned short* __restrict__ Xt,
                                               float* __restrict__ O) {
  __shared__ unsigned short Ab[128][32], Bb[128][32];
  const int tid = threadIdx.x;
  const int bb = blockIdx.z;
  const int l0 = blockIdx.y * 128, n0 = blockIdx.x * 128;
  const int lane = tid & 63;
  const int wr = (tid >> 7) & 1, wc = (tid >> 6) & 1;
  const int fr = lane & 15, kg = lane >> 4;
  f32x4 acc[4][4];
#pragma unroll
  for (int i = 0; i < 4; ++i)
#pragma unroll
    for (int j = 0; j < 4; ++j) acc[i][j] = 0;

  for (int kk = 0; kk < L_; kk += 32) {
    float4 av[4];
    uint4 bv[2];
#pragma unroll
    for (int p = 0; p < 4; ++p) {
      const int f = tid + p * 256;
      const int r = f >> 3, c = f & 7;
      av[p] = *(const float4*)(A + ((size_t)bb * L_ + l0 + r) * L_ + kk + c * 4);
    }
#pragma unroll
    for (int p = 0; p < 2; ++p) {
      const int f = tid + p * 256;
      const int r = f >> 2, sl = f & 3;
      bv[p] = *(const uint4*)(Xt + ((size_t)bb * D_ + n0 + r) * L_ + kk + sl * 8);
    }
    __syncthreads();
#pragma unroll
    for (int p = 0; p < 4; ++p) {
      const int f = tid + p * 256;
      const int r = f >> 3, c = f & 7;
      *(ushort4*)&Ab[r][c * 4] = make_ushort4(f2bf(av[p].x), f2bf(av[p].y),
                                              f2bf(av[p].z), f2bf(av[p].w));
    }
#pragma unroll
    for (int p = 0; p < 2; ++p) {
      const int f = tid + p * 256;
      const int r = f >> 2, sl = f & 3;
      *(uint4*)&Bb[r][sl * 8] = bv[p];
    }
    __syncthreads();
    bf16x8 fa[4], fb[4];
#pragma unroll
    for (int i = 0; i < 4; ++i) {
      fa[i] = *(const bf16x8*)&Ab[wr * 64 + i * 16 + fr][kg * 8];
      fb[i] = *(const bf16x8*)&Bb[wc * 64 + i * 16 + fr][kg * 8];
    }
#pragma unroll
    for (int i = 0; i < 4; ++i)
#pragma unroll
      for (int j = 0; j < 4; ++j)
        acc[i][j] = __builtin_amdgcn_mfma_f32_16x16x32_bf16(fa[i], fb[j], acc[i][j], 0, 0, 0);
  }
#pragma unroll
  for (int j = 0; j < 4; ++j) {
    const int gc = n0 + wc * 64 + j * 16 + fr;
#pragma unroll
    for (int i = 0; i < 4; ++i) {
      const int gl0 = l0 + wr * 64 + i * 16 + kg * 4;
#pragma unroll
      for (int r = 0; r < 4; ++r)
        O[((size_t)bb * L_ + gl0 + r) * D_ + gc] = acc[i][j][r];
    }
  }
}

// ---------------------------------------------------------------------------
extern "C" void kernel_launch(void* const* d_in, const int* in_sizes, int n_in,
                              void* d_out, int out_size, void* d_ws, size_t ws_size,
                              hipStream_t stream) {
  const float* X    = (const float*)d_in[0];  // [B,L,D]
  const void*  mraw = d_in[1];                // [B,L] bool/int
  const float* W    = (const float*)d_in[2];  // [D,D]
  const float* bias = (const float*)d_in[3];  // [D]

  float* out   = (float*)d_out;
  float* align = out;                          // B*L*D fp32
  float* alpha = out + (size_t)B_ * L_ * D_;   // B*L*L fp32

  // Ph,Pl (bf16, 25.2MB each) live in the align region (dead until k_align).
  unsigned short* Ph = (unsigned short*)align;
  unsigned short* Pl = Ph + (size_t)B_ * L_ * D_;

  int* maskC = (int*)d_ws;                                          // 64 KB
  unsigned short* Xt = (unsigned short*)((char*)d_ws + 65536);      // 25.2 MB

  hipLaunchKernelGGL(k_mask, dim3(1), dim3(256), 0, stream, mraw, maskC);
  hipLaunchKernelGGL(k_proj, dim3(D_ / 128, (B_ * L_) / 128), dim3(256), 0, stream,
                     X, W, bias, Ph, Pl);
  hipLaunchKernelGGL(k_scores, dim3(L_ / 128, L_ / 128, B_), dim3(256), 0, stream,
                     Ph, Pl, maskC, alpha);
  hipLaunchKernelGGL(k_softmax, dim3(B_ * L_), dim3(256), 0, stream, alpha);
  hipLaunchKernelGGL(k_transpose, dim3(D_ / 32, L_ / 32, B_), dim3(256), 0, stream,
                     X, Xt);
  hipLaunchKernelGGL(k_align, dim3(D_ / 128, L_ / 128, B_), dim3(256), 0, stream,
                     alpha, Xt, align);
}

// Round 3
// 494.319 us; speedup vs baseline: 1.9920x; 1.0729x over previous
//
#include <hip/hip_runtime.h>
#include <math.h>

// Problem constants
#define B_ 16
#define L_ 1024
#define D_ 768

typedef short bf16x8 __attribute__((ext_vector_type(8)));
typedef float f32x4 __attribute__((ext_vector_type(4)));

// round-to-nearest-even f32 -> bf16 (bit trick; inputs never NaN)
__device__ __forceinline__ unsigned short f2bf(float x) {
  unsigned u = __float_as_uint(x);
  u = (u + 0x7FFFu + ((u >> 16) & 1u)) >> 16;
  return (unsigned short)u;
}
__device__ __forceinline__ float bf2f(unsigned short h) {
  return __uint_as_float(((unsigned)h) << 16);
}

// ---------------------------------------------------------------------------
// K0: canonicalize mask (bool-bytes / int32 / int64 auto-detect). 1 = padding.
// ---------------------------------------------------------------------------
__global__ __launch_bounds__(256) void k_mask(const void* __restrict__ mraw,
                                              int* __restrict__ canon) {
  __shared__ int flags[2];
  if (threadIdx.x < 2) flags[threadIdx.x] = 0;
  __syncthreads();
  const unsigned* m32 = (const unsigned*)mraw;
  int gt = 0, oddnz = 0;
  for (int i = threadIdx.x; i < 4096; i += 256) {
    unsigned v = m32[i];
    if (v > 1u) gt = 1;
    if ((i & 1) && v != 0u) oddnz = 1;
  }
  if (gt) atomicOr(&flags[0], 1);
  if (oddnz) atomicOr(&flags[1], 1);
  __syncthreads();
  const int mode = flags[0] ? 0 : (flags[1] ? 1 : 2);  // 0=u8, 1=i32, 2=i64
  for (int i = threadIdx.x; i < B_ * L_; i += 256) {
    int v;
    if (mode == 0)      v = ((const unsigned char*)mraw)[i];
    else if (mode == 1) v = ((const int*)mraw)[i];
    else                v = (int)(((const long long*)mraw)[i] != 0);
    canon[i] = (v != 0);
  }
}

// ---------------------------------------------------------------------------
// K1 (MFMA): P = relu(X·W^T + b) -> bf16 hi/lo pair (Ph, Pl).
// 2-phase register-prefetch pipeline: loads for tile t+1 issued before the
// MFMA cluster of tile t; awaited only at the next LDS store.
// ---------------------------------------------------------------------------
__global__ __launch_bounds__(256) void k_proj(const float* __restrict__ X,
                                              const float* __restrict__ W,
                                              const float* __restrict__ bias,
                                              unsigned short* __restrict__ Ph,
                                              unsigned short* __restrict__ Pl) {
  __shared__ unsigned short Ah[128][32], Al[128][32], Bh[128][32], Bl[128][32];
  const int tid = threadIdx.x;
  const int m0 = blockIdx.y * 128, n0 = blockIdx.x * 128;
  const int lane = tid & 63;
  const int wr = (tid >> 7) & 1, wc = (tid >> 6) & 1;
  const int fr = lane & 15, kg = lane >> 4;
  f32x4 acc[4][4];
#pragma unroll
  for (int i = 0; i < 4; ++i)
#pragma unroll
    for (int j = 0; j < 4; ++j) acc[i][j] = 0;

  float4 av[4], bv[4];
#pragma unroll
  for (int p = 0; p < 4; ++p) {
    const int f = tid + p * 256, r = f >> 3, c = f & 7;
    av[p] = *(const float4*)(X + (size_t)(m0 + r) * D_ + c * 4);
    bv[p] = *(const float4*)(W + (size_t)(n0 + r) * D_ + c * 4);
  }

  for (int it = 0; it < D_ / 32; ++it) {
    __syncthreads();
#pragma unroll
    for (int p = 0; p < 4; ++p) {
      const int f = tid + p * 256, r = f >> 3, c = f & 7;
      {
        const float x0 = av[p].x, x1 = av[p].y, x2 = av[p].z, x3 = av[p].w;
        const unsigned short h0 = f2bf(x0), h1 = f2bf(x1), h2 = f2bf(x2), h3 = f2bf(x3);
        *(ushort4*)&Ah[r][c * 4] = make_ushort4(h0, h1, h2, h3);
        *(ushort4*)&Al[r][c * 4] = make_ushort4(f2bf(x0 - bf2f(h0)), f2bf(x1 - bf2f(h1)),
                                                f2bf(x2 - bf2f(h2)), f2bf(x3 - bf2f(h3)));
      }
      {
        const float x0 = bv[p].x, x1 = bv[p].y, x2 = bv[p].z, x3 = bv[p].w;
        const unsigned short h0 = f2bf(x0), h1 = f2bf(x1), h2 = f2bf(x2), h3 = f2bf(x3);
        *(ushort4*)&Bh[r][c * 4] = make_ushort4(h0, h1, h2, h3);
        *(ushort4*)&Bl[r][c * 4] = make_ushort4(f2bf(x0 - bf2f(h0)), f2bf(x1 - bf2f(h1)),
                                                f2bf(x2 - bf2f(h2)), f2bf(x3 - bf2f(h3)));
      }
    }
    __syncthreads();
    if (it + 1 < D_ / 32) {
      const int kk = (it + 1) * 32;
#pragma unroll
      for (int p = 0; p < 4; ++p) {
        const int f = tid + p * 256, r = f >> 3, c = f & 7;
        av[p] = *(const float4*)(X + (size_t)(m0 + r) * D_ + kk + c * 4);
        bv[p] = *(const float4*)(W + (size_t)(n0 + r) * D_ + kk + c * 4);
      }
    }
    bf16x8 fah[4], fal[4], fbh[4], fbl[4];
#pragma unroll
    for (int i = 0; i < 4; ++i) {
      fah[i] = *(const bf16x8*)&Ah[wr * 64 + i * 16 + fr][kg * 8];
      fal[i] = *(const bf16x8*)&Al[wr * 64 + i * 16 + fr][kg * 8];
      fbh[i] = *(const bf16x8*)&Bh[wc * 64 + i * 16 + fr][kg * 8];
      fbl[i] = *(const bf16x8*)&Bl[wc * 64 + i * 16 + fr][kg * 8];
    }
#pragma unroll
    for (int i = 0; i < 4; ++i)
#pragma unroll
      for (int j = 0; j < 4; ++j) {
        acc[i][j] = __builtin_amdgcn_mfma_f32_16x16x32_bf16(fah[i], fbh[j], acc[i][j], 0, 0, 0);
        acc[i][j] = __builtin_amdgcn_mfma_f32_16x16x32_bf16(fah[i], fbl[j], acc[i][j], 0, 0, 0);
        acc[i][j] = __builtin_amdgcn_mfma_f32_16x16x32_bf16(fal[i], fbh[j], acc[i][j], 0, 0, 0);
      }
  }
#pragma unroll
  for (int j = 0; j < 4; ++j) {
    const int gc = n0 + wc * 64 + j * 16 + fr;
    const float bb = bias[gc];
#pragma unroll
    for (int i = 0; i < 4; ++i) {
      const int gr0 = m0 + wr * 64 + i * 16 + kg * 4;
#pragma unroll
      for (int r = 0; r < 4; ++r) {
        float v = fmaxf(acc[i][j][r] + bb, 0.f);
        const unsigned short h = f2bf(v);
        Ph[(size_t)(gr0 + r) * D_ + gc] = h;
        Pl[(size_t)(gr0 + r) * D_ + gc] = f2bf(v - bf2f(h));
      }
    }
  }
}

// ---------------------------------------------------------------------------
// K2 (MFMA): S = P·P^T per batch — SYMMETRIC: only unordered tile pairs
// (36 of 64); the mirror tile is the exact transpose (the hi/lo decomposition
// is symmetric). Register-prefetch pipeline as in k_proj.
// Main tile (l0,m0): diag->0 (only possible when ti==tj), col mask[gm].
// Mirror tile (m0,l0): col mask[gl]; written as contiguous float4 per lane.
// ---------------------------------------------------------------------------
__global__ __launch_bounds__(256) void k_scores(const unsigned short* __restrict__ Ph,
                                                const unsigned short* __restrict__ Pl,
                                                const int* __restrict__ mask,
                                                float* __restrict__ S) {
  __shared__ unsigned short Ah[128][32], Al[128][32], Bh[128][32], Bl[128][32];
  const int tid = threadIdx.x;
  const int bb = blockIdx.z;
  // decode unordered pair index -> (ti, tj), tj <= ti
  int ti = 0;
  {
    const int idx = blockIdx.x;
    while ((ti + 1) * (ti + 2) / 2 <= idx) ++ti;
    ti = ti;
  }
  const int tj = blockIdx.x - ti * (ti + 1) / 2;
  const int l0 = ti * 128, m0 = tj * 128;
  const int lane = tid & 63;
  const int wr = (tid >> 7) & 1, wc = (tid >> 6) & 1;
  const int fr = lane & 15, kg = lane >> 4;
  f32x4 acc[4][4];
#pragma unroll
  for (int i = 0; i < 4; ++i)
#pragma unroll
    for (int j = 0; j < 4; ++j) acc[i][j] = 0;

  const size_t abase = ((size_t)bb * L_ + l0) * D_;
  const size_t bbase = ((size_t)bb * L_ + m0) * D_;
  uint4 va[2], vla[2], vb[2], vlb[2];
#pragma unroll
  for (int p = 0; p < 2; ++p) {
    const int f = tid + p * 256, r = f >> 2, sl = f & 3;
    va[p]  = *(const uint4*)(Ph + abase + (size_t)r * D_ + sl * 8);
    vla[p] = *(const uint4*)(Pl + abase + (size_t)r * D_ + sl * 8);
    vb[p]  = *(const uint4*)(Ph + bbase + (size_t)r * D_ + sl * 8);
    vlb[p] = *(const uint4*)(Pl + bbase + (size_t)r * D_ + sl * 8);
  }

  for (int it = 0; it < D_ / 32; ++it) {
    __syncthreads();
#pragma unroll
    for (int p = 0; p < 2; ++p) {
      const int f = tid + p * 256, r = f >> 2, sl = f & 3;
      *(uint4*)&Ah[r][sl * 8] = va[p];
      *(uint4*)&Al[r][sl * 8] = vla[p];
      *(uint4*)&Bh[r][sl * 8] = vb[p];
      *(uint4*)&Bl[r][sl * 8] = vlb[p];
    }
    __syncthreads();
    if (it + 1 < D_ / 32) {
      const int kk = (it + 1) * 32;
#pragma unroll
      for (int p = 0; p < 2; ++p) {
        const int f = tid + p * 256, r = f >> 2, sl = f & 3;
        va[p]  = *(const uint4*)(Ph + abase + (size_t)r * D_ + kk + sl * 8);
        vla[p] = *(const uint4*)(Pl + abase + (size_t)r * D_ + kk + sl * 8);
        vb[p]  = *(const uint4*)(Ph + bbase + (size_t)r * D_ + kk + sl * 8);
        vlb[p] = *(const uint4*)(Pl + bbase + (size_t)r * D_ + kk + sl * 8);
      }
    }
    bf16x8 fah[4], fal[4], fbh[4], fbl[4];
#pragma unroll
    for (int i = 0; i < 4; ++i) {
      fah[i] = *(const bf16x8*)&Ah[wr * 64 + i * 16 + fr][kg * 8];
      fal[i] = *(const bf16x8*)&Al[wr * 64 + i * 16 + fr][kg * 8];
      fbh[i] = *(const bf16x8*)&Bh[wc * 64 + i * 16 + fr][kg * 8];
      fbl[i] = *(const bf16x8*)&Bl[wc * 64 + i * 16 + fr][kg * 8];
    }
#pragma unroll
    for (int i = 0; i < 4; ++i)
#pragma unroll
      for (int j = 0; j < 4; ++j) {
        acc[i][j] = __builtin_amdgcn_mfma_f32_16x16x32_bf16(fah[i], fbh[j], acc[i][j], 0, 0, 0);
        acc[i][j] = __builtin_amdgcn_mfma_f32_16x16x32_bf16(fah[i], fbl[j], acc[i][j], 0, 0, 0);
        acc[i][j] = __builtin_amdgcn_mfma_f32_16x16x32_bf16(fal[i], fbh[j], acc[i][j], 0, 0, 0);
      }
  }

  // ---- main tile: S[gl][gm] ----
#pragma unroll
  for (int j = 0; j < 4; ++j) {
    const int gm = m0 + wc * 64 + j * 16 + fr;
    const int mk = mask[bb * L_ + gm];
#pragma unroll
    for (int i = 0; i < 4; ++i) {
      const int gl0 = l0 + wr * 64 + i * 16 + kg * 4;
#pragma unroll
      for (int r = 0; r < 4; ++r) {
        const int gl = gl0 + r;
        float v = acc[i][j][r];
        if (gm == gl) v = 0.f;          // only reachable when ti==tj
        if (mk) v = -INFINITY;
        S[((size_t)bb * L_ + gl) * L_ + gm] = v;
      }
    }
  }
  // ---- mirror tile: S[gm][gl] = same values, key mask on gl ----
  if (ti != tj) {
#pragma unroll
    for (int i = 0; i < 4; ++i) {
      const int gl0 = l0 + wr * 64 + i * 16 + kg * 4;
      const int4 mrow = *(const int4*)(mask + bb * L_ + gl0);
#pragma unroll
      for (int j = 0; j < 4; ++j) {
        const int gm = m0 + wc * 64 + j * 16 + fr;
        float4 o;
        o.x = mrow.x ? -INFINITY : acc[i][j][0];
        o.y = mrow.y ? -INFINITY : acc[i][j][1];
        o.z = mrow.z ? -INFINITY : acc[i][j][2];
        o.w = mrow.w ? -INFINITY : acc[i][j][3];
        *(float4*)(S + ((size_t)bb * L_ + gm) * L_ + gl0) = o;
      }
    }
  }
}

// ---------------------------------------------------------------------------
// K3: in-place row softmax over 1024 keys.
// ---------------------------------------------------------------------------
__global__ __launch_bounds__(256) void k_softmax(float* __restrict__ S) {
  const size_t row = blockIdx.x;
  float4* rp = (float4*)(S + row * L_);
  float4 v = rp[threadIdx.x];
  float mx = fmaxf(fmaxf(v.x, v.y), fmaxf(v.z, v.w));
#pragma unroll
  for (int o = 32; o > 0; o >>= 1) mx = fmaxf(mx, __shfl_xor(mx, o));
  __shared__ float rmax[4], rsum[4];
  const int wv = threadIdx.x >> 6, ln = threadIdx.x & 63;
  if (ln == 0) rmax[wv] = mx;
  __syncthreads();
  mx = fmaxf(fmaxf(rmax[0], rmax[1]), fmaxf(rmax[2], rmax[3]));
  float4 e;
  e.x = __expf(v.x - mx); e.y = __expf(v.y - mx);
  e.z = __expf(v.z - mx); e.w = __expf(v.w - mx);
  float s = (e.x + e.y) + (e.z + e.w);
#pragma unroll
  for (int o = 32; o > 0; o >>= 1) s += __shfl_xor(s, o);
  if (ln == 0) rsum[wv] = s;
  __syncthreads();
  s = (rsum[0] + rsum[1]) + (rsum[2] + rsum[3]);
  const float inv = 1.0f / s;
  e.x *= inv; e.y *= inv; e.z *= inv; e.w *= inv;
  rp[threadIdx.x] = e;
}

// ---------------------------------------------------------------------------
// K4: Xt[b][d][m] = bf16(X[b][m][d])
// ---------------------------------------------------------------------------
__global__ __launch_bounds__(256) void k_transpose(const float* __restrict__ X,
                                                   unsigned short* __restrict__ Xt) {
  __shared__ float t[32][33];
  const int b = blockIdx.z;
  const int d0 = blockIdx.x * 32, m0 = blockIdx.y * 32;
  const int tx = threadIdx.x & 31, ty = threadIdx.x >> 5;
#pragma unroll
  for (int i = 0; i < 32; i += 8)
    t[ty + i][tx] = X[((size_t)b * L_ + m0 + ty + i) * D_ + d0 + tx];
  __syncthreads();
#pragma unroll
  for (int i = 0; i < 32; i += 8)
    Xt[((size_t)b * D_ + d0 + ty + i) * L_ + m0 + tx] = f2bf(t[tx][ty + i]);
}

// ---------------------------------------------------------------------------
// K5 (MFMA): align = alpha·X per batch, register-prefetch pipeline.
// ---------------------------------------------------------------------------
__global__ __launch_bounds__(256) void k_align(const float* __restrict__ A,
                                               const unsigned short* __restrict__ Xt,
                                               float* __restrict__ O) {
  __shared__ unsigned short Ab[128][32], Bb[128][32];
  const int tid = threadIdx.x;
  const int bb = blockIdx.z;
  const int l0 = blockIdx.y * 128, n0 = blockIdx.x * 128;
  const int lane = tid & 63;
  const int wr = (tid >> 7) & 1, wc = (tid >> 6) & 1;
  const int fr = lane & 15, kg = lane >> 4;
  f32x4 acc[4][4];
#pragma unroll
  for (int i = 0; i < 4; ++i)
#pragma unroll
    for (int j = 0; j < 4; ++j) acc[i][j] = 0;

  float4 av[4];
  uint4 bv[2];
#pragma unroll
  for (int p = 0; p < 4; ++p) {
    const int f = tid + p * 256, r = f >> 3, c = f & 7;
    av[p] = *(const float4*)(A + ((size_t)bb * L_ + l0 + r) * L_ + c * 4);
  }
#pragma unroll
  for (int p = 0; p < 2; ++p) {
    const int f = tid + p * 256, r = f >> 2, sl = f & 3;
    bv[p] = *(const uint4*)(Xt + ((size_t)bb * D_ + n0 + r) * L_ + sl * 8);
  }

  for (int it = 0; it < L_ / 32; ++it) {
    __syncthreads();
#pragma unroll
    for (int p = 0; p < 4; ++p) {
      const int f = tid + p * 256, r = f >> 3, c = f & 7;
      *(ushort4*)&Ab[r][c * 4] = make_ushort4(f2bf(av[p].x), f2bf(av[p].y),
                                              f2bf(av[p].z), f2bf(av[p].w));
    }
#pragma unroll
    for (int p = 0; p < 2; ++p) {
      const int f = tid + p * 256, r = f >> 2, sl = f & 3;
      *(uint4*)&Bb[r][sl * 8] = bv[p];
    }
    __syncthreads();
    if (it + 1 < L_ / 32) {
      const int kk = (it + 1) * 32;
#pragma unroll
      for (int p = 0; p < 4; ++p) {
        const int f = tid + p * 256, r = f >> 3, c = f & 7;
        av[p] = *(const float4*)(A + ((size_t)bb * L_ + l0 + r) * L_ + kk + c * 4);
      }
#pragma unroll
      for (int p = 0; p < 2; ++p) {
        const int f = tid + p * 256, r = f >> 2, sl = f & 3;
        bv[p] = *(const uint4*)(Xt + ((size_t)bb * D_ + n0 + r) * L_ + kk + sl * 8);
      }
    }
    bf16x8 fa[4], fb[4];
#pragma unroll
    for (int i = 0; i < 4; ++i) {
      fa[i] = *(const bf16x8*)&Ab[wr * 64 + i * 16 + fr][kg * 8];
      fb[i] = *(const bf16x8*)&Bb[wc * 64 + i * 16 + fr][kg * 8];
    }
#pragma unroll
    for (int i = 0; i < 4; ++i)
#pragma unroll
      for (int j = 0; j < 4; ++j)
        acc[i][j] = __builtin_amdgcn_mfma_f32_16x16x32_bf16(fa[i], fb[j], acc[i][j], 0, 0, 0);
  }
#pragma unroll
  for (int j = 0; j < 4; ++j) {
    const int gc = n0 + wc * 64 + j * 16 + fr;
#pragma unroll
    for (int i = 0; i < 4; ++i) {
      const int gl0 = l0 + wr * 64 + i * 16 + kg * 4;
#pragma unroll
      for (int r = 0; r < 4; ++r)
        O[((size_t)bb * L_ + gl0 + r) * D_ + gc] = acc[i][j][r];
    }
  }
}

// ---------------------------------------------------------------------------
extern "C" void kernel_launch(void* const* d_in, const int* in_sizes, int n_in,
                              void* d_out, int out_size, void* d_ws, size_t ws_size,
                              hipStream_t stream) {
  const float* X    = (const float*)d_in[0];  // [B,L,D]
  const void*  mraw = d_in[1];                // [B,L] bool/int
  const float* W    = (const float*)d_in[2];  // [D,D]
  const float* bias = (const float*)d_in[3];  // [D]

  float* out   = (float*)d_out;
  float* align = out;                          // B*L*D fp32
  float* alpha = out + (size_t)B_ * L_ * D_;   // B*L*L fp32

  // Ph,Pl (bf16, 25.2MB each) live in the align region (dead until k_align).
  unsigned short* Ph = (unsigned short*)align;
  unsigned short* Pl = Ph + (size_t)B_ * L_ * D_;

  int* maskC = (int*)d_ws;                                          // 64 KB
  unsigned short* Xt = (unsigned short*)((char*)d_ws + 65536);      // 25.2 MB

  hipLaunchKernelGGL(k_mask, dim3(1), dim3(256), 0, stream, mraw, maskC);
  hipLaunchKernelGGL(k_proj, dim3(D_ / 128, (B_ * L_) / 128), dim3(256), 0, stream,
                     X, W, bias, Ph, Pl);
  hipLaunchKernelGGL(k_scores, dim3(36, 1, B_), dim3(256), 0, stream,
                     Ph, Pl, maskC, alpha);
  hipLaunchKernelGGL(k_softmax, dim3(B_ * L_), dim3(256), 0, stream, alpha);
  hipLaunchKernelGGL(k_transpose, dim3(D_ / 32, L_ / 32, B_), dim3(256), 0, stream,
                     X, Xt);
  hipLaunchKernelGGL(k_align, dim3(D_ / 128, L_ / 128, B_), dim3(256), 0, stream,
                     alpha, Xt, align);
}

// Round 4
// 424.426 us; speedup vs baseline: 2.3200x; 1.1647x over previous
//
#include <hip/hip_runtime.h>
#include <math.h>

// Problem constants
#define B_ 16
#define L_ 1024
#define D_ 768

typedef short bf16x8 __attribute__((ext_vector_type(8)));
typedef float f32x4 __attribute__((ext_vector_type(4)));

// round-to-nearest-even f32 -> bf16 (bit trick; inputs never NaN)
__device__ __forceinline__ unsigned short f2bf(float x) {
  unsigned u = __float_as_uint(x);
  u = (u + 0x7FFFu + ((u >> 16) & 1u)) >> 16;
  return (unsigned short)u;
}
__device__ __forceinline__ float bf2f(unsigned short h) {
  return __uint_as_float(((unsigned)h) << 16);
}

// ---------------------------------------------------------------------------
// K0: canonicalize mask (bool-bytes / int32 / int64 auto-detect). 1 = padding.
// ---------------------------------------------------------------------------
__global__ __launch_bounds__(256) void k_mask(const void* __restrict__ mraw,
                                              int* __restrict__ canon) {
  __shared__ int flags[2];
  if (threadIdx.x < 2) flags[threadIdx.x] = 0;
  __syncthreads();
  const unsigned* m32 = (const unsigned*)mraw;
  int gt = 0, oddnz = 0;
  for (int i = threadIdx.x; i < 4096; i += 256) {
    unsigned v = m32[i];
    if (v > 1u) gt = 1;
    if ((i & 1) && v != 0u) oddnz = 1;
  }
  if (gt) atomicOr(&flags[0], 1);
  if (oddnz) atomicOr(&flags[1], 1);
  __syncthreads();
  const int mode = flags[0] ? 0 : (flags[1] ? 1 : 2);  // 0=u8, 1=i32, 2=i64
  for (int i = threadIdx.x; i < B_ * L_; i += 256) {
    int v;
    if (mode == 0)      v = ((const unsigned char*)mraw)[i];
    else if (mode == 1) v = ((const int*)mraw)[i];
    else                v = (int)(((const long long*)mraw)[i] != 0);
    canon[i] = (v != 0);
  }
}

// ---------------------------------------------------------------------------
// K1 (MFMA): P = relu(X·W^T + b) -> bf16 hi/lo (Ph, Pl).
// Register-prefetch pipeline + LDS-transposed coalesced epilogue (32B/lane).
// 1D grid 768 = 128 m-tiles x 6 n-tiles, XCD-swizzled (96 blocks/XCD).
// ---------------------------------------------------------------------------
__global__ __launch_bounds__(256) void k_proj(const float* __restrict__ X,
                                              const float* __restrict__ W,
                                              const float* __restrict__ bias,
                                              unsigned short* __restrict__ Ph,
                                              unsigned short* __restrict__ Pl) {
  __shared__ __align__(16) unsigned short smem[4 * 128 * 32];  // 32 KB
  unsigned short (*Ah)[32] = (unsigned short(*)[32])smem;
  unsigned short (*Al)[32] = (unsigned short(*)[32])(smem + 1 * 128 * 32);
  unsigned short (*Bh)[32] = (unsigned short(*)[32])(smem + 2 * 128 * 32);
  unsigned short (*Bl)[32] = (unsigned short(*)[32])(smem + 3 * 128 * 32);

  const int tid = threadIdx.x;
  const int swz = ((int)blockIdx.x % 8) * 96 + (int)blockIdx.x / 8;
  const int m0 = (swz / 6) * 128, n0 = (swz % 6) * 128;
  const int lane = tid & 63, wave = tid >> 6;
  const int wr = wave >> 1, wc = wave & 1;
  const int fr = lane & 15, kg = lane >> 4;
  f32x4 acc[4][4];
#pragma unroll
  for (int i = 0; i < 4; ++i)
#pragma unroll
    for (int j = 0; j < 4; ++j) acc[i][j] = 0;

  float4 av[4], bv[4];
#pragma unroll
  for (int p = 0; p < 4; ++p) {
    const int f = tid + p * 256, r = f >> 3, c = f & 7;
    av[p] = *(const float4*)(X + (size_t)(m0 + r) * D_ + c * 4);
    bv[p] = *(const float4*)(W + (size_t)(n0 + r) * D_ + c * 4);
  }

  for (int it = 0; it < D_ / 32; ++it) {
    __syncthreads();
#pragma unroll
    for (int p = 0; p < 4; ++p) {
      const int f = tid + p * 256, r = f >> 3, c = f & 7;
      {
        const float x0 = av[p].x, x1 = av[p].y, x2 = av[p].z, x3 = av[p].w;
        const unsigned short h0 = f2bf(x0), h1 = f2bf(x1), h2 = f2bf(x2), h3 = f2bf(x3);
        *(ushort4*)&Ah[r][c * 4] = make_ushort4(h0, h1, h2, h3);
        *(ushort4*)&Al[r][c * 4] = make_ushort4(f2bf(x0 - bf2f(h0)), f2bf(x1 - bf2f(h1)),
                                                f2bf(x2 - bf2f(h2)), f2bf(x3 - bf2f(h3)));
      }
      {
        const float x0 = bv[p].x, x1 = bv[p].y, x2 = bv[p].z, x3 = bv[p].w;
        const unsigned short h0 = f2bf(x0), h1 = f2bf(x1), h2 = f2bf(x2), h3 = f2bf(x3);
        *(ushort4*)&Bh[r][c * 4] = make_ushort4(h0, h1, h2, h3);
        *(ushort4*)&Bl[r][c * 4] = make_ushort4(f2bf(x0 - bf2f(h0)), f2bf(x1 - bf2f(h1)),
                                                f2bf(x2 - bf2f(h2)), f2bf(x3 - bf2f(h3)));
      }
    }
    __syncthreads();
    if (it + 1 < D_ / 32) {
      const int kk = (it + 1) * 32;
#pragma unroll
      for (int p = 0; p < 4; ++p) {
        const int f = tid + p * 256, r = f >> 3, c = f & 7;
        av[p] = *(const float4*)(X + (size_t)(m0 + r) * D_ + kk + c * 4);
        bv[p] = *(const float4*)(W + (size_t)(n0 + r) * D_ + kk + c * 4);
      }
    }
    bf16x8 fah[4], fal[4], fbh[4], fbl[4];
#pragma unroll
    for (int i = 0; i < 4; ++i) {
      fah[i] = *(const bf16x8*)&Ah[wr * 64 + i * 16 + fr][kg * 8];
      fal[i] = *(const bf16x8*)&Al[wr * 64 + i * 16 + fr][kg * 8];
      fbh[i] = *(const bf16x8*)&Bh[wc * 64 + i * 16 + fr][kg * 8];
      fbl[i] = *(const bf16x8*)&Bl[wc * 64 + i * 16 + fr][kg * 8];
    }
#pragma unroll
    for (int i = 0; i < 4; ++i)
#pragma unroll
      for (int j = 0; j < 4; ++j) {
        acc[i][j] = __builtin_amdgcn_mfma_f32_16x16x32_bf16(fah[i], fbh[j], acc[i][j], 0, 0, 0);
        acc[i][j] = __builtin_amdgcn_mfma_f32_16x16x32_bf16(fah[i], fbl[j], acc[i][j], 0, 0, 0);
        acc[i][j] = __builtin_amdgcn_mfma_f32_16x16x32_bf16(fal[i], fbh[j], acc[i][j], 0, 0, 0);
      }
  }

  // Epilogue: bias+relu+split in regs; transpose via LDS; 2x uint4 per lane
  // per output array -> full 128B-line coalescing.
  unsigned short* scr = smem + wave * 2304;  // [2][16][72] ushort per wave
  const int row = lane >> 2, seg = lane & 3;
  float bj[4];
#pragma unroll
  for (int j = 0; j < 4; ++j) bj[j] = bias[n0 + wc * 64 + j * 16 + fr];
  for (int i = 0; i < 4; ++i) {
    __syncthreads();
#pragma unroll
    for (int j = 0; j < 4; ++j)
#pragma unroll
      for (int r = 0; r < 4; ++r) {
        float v = fmaxf(acc[i][j][r] + bj[j], 0.f);
        const unsigned short h = f2bf(v);
        scr[(kg * 4 + r) * 72 + j * 16 + fr] = h;
        scr[1152 + (kg * 4 + r) * 72 + j * 16 + fr] = f2bf(v - bf2f(h));
      }
    __syncthreads();
    const size_t gr = (size_t)(m0 + wr * 64 + i * 16 + row);
    const int gc0 = n0 + wc * 64 + seg * 16;
    const uint4 h0 = *(const uint4*)&scr[row * 72 + seg * 16];
    const uint4 h1 = *(const uint4*)&scr[row * 72 + seg * 16 + 8];
    const uint4 q0 = *(const uint4*)&scr[1152 + row * 72 + seg * 16];
    const uint4 q1 = *(const uint4*)&scr[1152 + row * 72 + seg * 16 + 8];
    *(uint4*)(Ph + gr * D_ + gc0)     = h0;
    *(uint4*)(Ph + gr * D_ + gc0 + 8) = h1;
    *(uint4*)(Pl + gr * D_ + gc0)     = q0;
    *(uint4*)(Pl + gr * D_ + gc0 + 8) = q1;
  }
}

// ---------------------------------------------------------------------------
// K2 (MFMA): S = P·P^T, symmetric tile pairs (36/64). LDS-transposed
// coalesced main writes (64B x4 per lane) + 64B/lane mirror writes.
// 1D grid 576 = 16 batches x 36 pairs, XCD-swizzled (72 blocks = 2 batches/XCD).
// ---------------------------------------------------------------------------
__global__ __launch_bounds__(256) void k_scores(const unsigned short* __restrict__ Ph,
                                                const unsigned short* __restrict__ Pl,
                                                const int* __restrict__ mask,
                                                float* __restrict__ S) {
  __shared__ __align__(16) unsigned short smem[4 * 128 * 32];  // 32 KB
  unsigned short (*Ah)[32] = (unsigned short(*)[32])smem;
  unsigned short (*Al)[32] = (unsigned short(*)[32])(smem + 1 * 128 * 32);
  unsigned short (*Bh)[32] = (unsigned short(*)[32])(smem + 2 * 128 * 32);
  unsigned short (*Bl)[32] = (unsigned short(*)[32])(smem + 3 * 128 * 32);

  const int tid = threadIdx.x;
  const int swz = ((int)blockIdx.x % 8) * 72 + (int)blockIdx.x / 8;
  const int bb = swz / 36;
  const int pr = swz % 36;
  int ti = 0;
  while ((ti + 1) * (ti + 2) / 2 <= pr) ++ti;
  const int tj = pr - ti * (ti + 1) / 2;
  const int l0 = ti * 128, m0 = tj * 128;
  const int lane = tid & 63, wave = tid >> 6;
  const int wr = wave >> 1, wc = wave & 1;
  const int fr = lane & 15, kg = lane >> 4;
  f32x4 acc[4][4];
#pragma unroll
  for (int i = 0; i < 4; ++i)
#pragma unroll
    for (int j = 0; j < 4; ++j) acc[i][j] = 0;

  const size_t abase = ((size_t)bb * L_ + l0) * D_;
  const size_t bbase = ((size_t)bb * L_ + m0) * D_;
  uint4 va[2], vla[2], vb[2], vlb[2];
#pragma unroll
  for (int p = 0; p < 2; ++p) {
    const int f = tid + p * 256, r = f >> 2, sl = f & 3;
    va[p]  = *(const uint4*)(Ph + abase + (size_t)r * D_ + sl * 8);
    vla[p] = *(const uint4*)(Pl + abase + (size_t)r * D_ + sl * 8);
    vb[p]  = *(const uint4*)(Ph + bbase + (size_t)r * D_ + sl * 8);
    vlb[p] = *(const uint4*)(Pl + bbase + (size_t)r * D_ + sl * 8);
  }

  for (int it = 0; it < D_ / 32; ++it) {
    __syncthreads();
#pragma unroll
    for (int p = 0; p < 2; ++p) {
      const int f = tid + p * 256, r = f >> 2, sl = f & 3;
      *(uint4*)&Ah[r][sl * 8] = va[p];
      *(uint4*)&Al[r][sl * 8] = vla[p];
      *(uint4*)&Bh[r][sl * 8] = vb[p];
      *(uint4*)&Bl[r][sl * 8] = vlb[p];
    }
    __syncthreads();
    if (it + 1 < D_ / 32) {
      const int kk = (it + 1) * 32;
#pragma unroll
      for (int p = 0; p < 2; ++p) {
        const int f = tid + p * 256, r = f >> 2, sl = f & 3;
        va[p]  = *(const uint4*)(Ph + abase + (size_t)r * D_ + kk + sl * 8);
        vla[p] = *(const uint4*)(Pl + abase + (size_t)r * D_ + kk + sl * 8);
        vb[p]  = *(const uint4*)(Ph + bbase + (size_t)r * D_ + kk + sl * 8);
        vlb[p] = *(const uint4*)(Pl + bbase + (size_t)r * D_ + kk + sl * 8);
      }
    }
    bf16x8 fah[4], fal[4], fbh[4], fbl[4];
#pragma unroll
    for (int i = 0; i < 4; ++i) {
      fah[i] = *(const bf16x8*)&Ah[wr * 64 + i * 16 + fr][kg * 8];
      fal[i] = *(const bf16x8*)&Al[wr * 64 + i * 16 + fr][kg * 8];
      fbh[i] = *(const bf16x8*)&Bh[wc * 64 + i * 16 + fr][kg * 8];
      fbl[i] = *(const bf16x8*)&Bl[wc * 64 + i * 16 + fr][kg * 8];
    }
#pragma unroll
    for (int i = 0; i < 4; ++i)
#pragma unroll
      for (int j = 0; j < 4; ++j) {
        acc[i][j] = __builtin_amdgcn_mfma_f32_16x16x32_bf16(fah[i], fbh[j], acc[i][j], 0, 0, 0);
        acc[i][j] = __builtin_amdgcn_mfma_f32_16x16x32_bf16(fah[i], fbl[j], acc[i][j], 0, 0, 0);
        acc[i][j] = __builtin_amdgcn_mfma_f32_16x16x32_bf16(fal[i], fbh[j], acc[i][j], 0, 0, 0);
      }
  }

  // Epilogue. Per-wave scratch region: 1280 floats (5120B, 16B-aligned).
  float* scr = ((float*)smem) + wave * 1280;
  const int row = lane >> 2, seg = lane & 3;

  // ---- main tile (rows l, cols m), transposed in LDS, coalesced rows ----
  for (int i = 0; i < 4; ++i) {
    __syncthreads();
#pragma unroll
    for (int j = 0; j < 4; ++j)
#pragma unroll
      for (int r = 0; r < 4; ++r)
        scr[(kg * 4 + r) * 68 + j * 16 + fr] = acc[i][j][r];
    __syncthreads();
    const int gl = l0 + wr * 64 + i * 16 + row;
    const int gm0 = m0 + wc * 64 + seg * 16;
    const size_t sbase = ((size_t)bb * L_ + gl) * L_ + gm0;
#pragma unroll
    for (int t = 0; t < 4; ++t) {
      float4 o = *(const float4*)&scr[row * 68 + seg * 16 + t * 4];
      const int4 mk = *(const int4*)(mask + bb * L_ + gm0 + t * 4);
      float* op = (float*)&o;
      const int* mp = (const int*)&mk;
#pragma unroll
      for (int e = 0; e < 4; ++e) {
        const int gm = gm0 + t * 4 + e;
        if (gm == gl) op[e] = 0.f;
        if (mp[e]) op[e] = -INFINITY;
      }
      *(float4*)(S + sbase + t * 4) = o;
    }
  }

  // ---- mirror tile (rows m, cols l): frag-native layout in LDS [64][20] ----
  if (ti != tj) {
    for (int i = 0; i < 4; ++i) {
      __syncthreads();
#pragma unroll
      for (int j = 0; j < 4; ++j)
#pragma unroll
        for (int r = 0; r < 4; ++r)
          scr[(j * 16 + fr) * 20 + kg * 4 + r] = acc[i][j][r];
      __syncthreads();
      const int gm = m0 + wc * 64 + lane;
      const int gl0 = l0 + wr * 64 + i * 16;
      const size_t sbase = ((size_t)bb * L_ + gm) * L_ + gl0;
#pragma unroll
      for (int t = 0; t < 4; ++t) {
        float4 o = *(const float4*)&scr[lane * 20 + t * 4];
        const int4 mk = *(const int4*)(mask + bb * L_ + gl0 + t * 4);
        float* op = (float*)&o;
        const int* mp = (const int*)&mk;
#pragma unroll
        for (int e = 0; e < 4; ++e)
          if (mp[e]) op[e] = -INFINITY;
        *(float4*)(S + sbase + t * 4) = o;
      }
    }
  }
}

// ---------------------------------------------------------------------------
// K3: in-place row softmax over 1024 keys.
// ---------------------------------------------------------------------------
__global__ __launch_bounds__(256) void k_softmax(float* __restrict__ S) {
  const size_t row = blockIdx.x;
  float4* rp = (float4*)(S + row * L_);
  float4 v = rp[threadIdx.x];
  float mx = fmaxf(fmaxf(v.x, v.y), fmaxf(v.z, v.w));
#pragma unroll
  for (int o = 32; o > 0; o >>= 1) mx = fmaxf(mx, __shfl_xor(mx, o));
  __shared__ float rmax[4], rsum[4];
  const int wv = threadIdx.x >> 6, ln = threadIdx.x & 63;
  if (ln == 0) rmax[wv] = mx;
  __syncthreads();
  mx = fmaxf(fmaxf(rmax[0], rmax[1]), fmaxf(rmax[2], rmax[3]));
  float4 e;
  e.x = __expf(v.x - mx); e.y = __expf(v.y - mx);
  e.z = __expf(v.z - mx); e.w = __expf(v.w - mx);
  float s = (e.x + e.y) + (e.z + e.w);
#pragma unroll
  for (int o = 32; o > 0; o >>= 1) s += __shfl_xor(s, o);
  if (ln == 0) rsum[wv] = s;
  __syncthreads();
  s = (rsum[0] + rsum[1]) + (rsum[2] + rsum[3]);
  const float inv = 1.0f / s;
  e.x *= inv; e.y *= inv; e.z *= inv; e.w *= inv;
  rp[threadIdx.x] = e;
}

// ---------------------------------------------------------------------------
// K4: Xt[b][d][m] = bf16(X[b][m][d])
// ---------------------------------------------------------------------------
__global__ __launch_bounds__(256) void k_transpose(const float* __restrict__ X,
                                                   unsigned short* __restrict__ Xt) {
  __shared__ float t[32][33];
  const int b = blockIdx.z;
  const int d0 = blockIdx.x * 32, m0 = blockIdx.y * 32;
  const int tx = threadIdx.x & 31, ty = threadIdx.x >> 5;
#pragma unroll
  for (int i = 0; i < 32; i += 8)
    t[ty + i][tx] = X[((size_t)b * L_ + m0 + ty + i) * D_ + d0 + tx];
  __syncthreads();
#pragma unroll
  for (int i = 0; i < 32; i += 8)
    Xt[((size_t)b * D_ + d0 + ty + i) * L_ + m0 + tx] = f2bf(t[tx][ty + i]);
}

// ---------------------------------------------------------------------------
// K5 (MFMA): align = alpha·X per batch; LDS-transposed coalesced f32 writes.
// 1D grid 768 = 16 batches x 8 l-tiles x 6 n-tiles, XCD-swizzled.
// ---------------------------------------------------------------------------
__global__ __launch_bounds__(256) void k_align(const float* __restrict__ A,
                                               const unsigned short* __restrict__ Xt,
                                               float* __restrict__ O) {
  __shared__ __align__(16) unsigned short smem[2 * 128 * 32];  // 16 KB staging
  __shared__ __align__(16) float scr_s[4 * 1104];              // 17.7 KB scratch
  unsigned short (*Ab)[32] = (unsigned short(*)[32])smem;
  unsigned short (*Bb)[32] = (unsigned short(*)[32])(smem + 128 * 32);

  const int tid = threadIdx.x;
  const int swz = ((int)blockIdx.x % 8) * 96 + (int)blockIdx.x / 8;
  const int bb = swz / 48;
  const int l0 = ((swz / 6) % 8) * 128;
  const int n0 = (swz % 6) * 128;
  const int lane = tid & 63, wave = tid >> 6;
  const int wr = wave >> 1, wc = wave & 1;
  const int fr = lane & 15, kg = lane >> 4;
  f32x4 acc[4][4];
#pragma unroll
  for (int i = 0; i < 4; ++i)
#pragma unroll
    for (int j = 0; j < 4; ++j) acc[i][j] = 0;

  float4 av[4];
  uint4 bv[2];
#pragma unroll
  for (int p = 0; p < 4; ++p) {
    const int f = tid + p * 256, r = f >> 3, c = f & 7;
    av[p] = *(const float4*)(A + ((size_t)bb * L_ + l0 + r) * L_ + c * 4);
  }
#pragma unroll
  for (int p = 0; p < 2; ++p) {
    const int f = tid + p * 256, r = f >> 2, sl = f & 3;
    bv[p] = *(const uint4*)(Xt + ((size_t)bb * D_ + n0 + r) * L_ + sl * 8);
  }

  for (int it = 0; it < L_ / 32; ++it) {
    __syncthreads();
#pragma unroll
    for (int p = 0; p < 4; ++p) {
      const int f = tid + p * 256, r = f >> 3, c = f & 7;
      *(ushort4*)&Ab[r][c * 4] = make_ushort4(f2bf(av[p].x), f2bf(av[p].y),
                                              f2bf(av[p].z), f2bf(av[p].w));
    }
#pragma unroll
    for (int p = 0; p < 2; ++p) {
      const int f = tid + p * 256, r = f >> 2, sl = f & 3;
      *(uint4*)&Bb[r][sl * 8] = bv[p];
    }
    __syncthreads();
    if (it + 1 < L_ / 32) {
      const int kk = (it + 1) * 32;
#pragma unroll
      for (int p = 0; p < 4; ++p) {
        const int f = tid + p * 256, r = f >> 3, c = f & 7;
        av[p] = *(const float4*)(A + ((size_t)bb * L_ + l0 + r) * L_ + kk + c * 4);
      }
#pragma unroll
      for (int p = 0; p < 2; ++p) {
        const int f = tid + p * 256, r = f >> 2, sl = f & 3;
        bv[p] = *(const uint4*)(Xt + ((size_t)bb * D_ + n0 + r) * L_ + kk + sl * 8);
      }
    }
    bf16x8 fa[4], fb[4];
#pragma unroll
    for (int i = 0; i < 4; ++i) {
      fa[i] = *(const bf16x8*)&Ab[wr * 64 + i * 16 + fr][kg * 8];
      fb[i] = *(const bf16x8*)&Bb[wc * 64 + i * 16 + fr][kg * 8];
    }
#pragma unroll
    for (int i = 0; i < 4; ++i)
#pragma unroll
      for (int j = 0; j < 4; ++j)
        acc[i][j] = __builtin_amdgcn_mfma_f32_16x16x32_bf16(fa[i], fb[j], acc[i][j], 0, 0, 0);
  }

  // Epilogue: LDS transpose -> 4x float4 per lane, row-contiguous.
  float* scr = scr_s + wave * 1104;
  const int row = lane >> 2, seg = lane & 3;
  for (int i = 0; i < 4; ++i) {
    __syncthreads();
#pragma unroll
    for (int j = 0; j < 4; ++j)
#pragma unroll
      for (int r = 0; r < 4; ++r)
        scr[(kg * 4 + r) * 68 + j * 16 + fr] = acc[i][j][r];
    __syncthreads();
    const int gl = l0 + wr * 64 + i * 16 + row;
    const int gc0 = n0 + wc * 64 + seg * 16;
    const size_t obase = ((size_t)bb * L_ + gl) * D_ + gc0;
#pragma unroll
    for (int t = 0; t < 4; ++t) {
      const float4 o = *(const float4*)&scr[row * 68 + seg * 16 + t * 4];
      *(float4*)(O + obase + t * 4) = o;
    }
  }
}

// ---------------------------------------------------------------------------
extern "C" void kernel_launch(void* const* d_in, const int* in_sizes, int n_in,
                              void* d_out, int out_size, void* d_ws, size_t ws_size,
                              hipStream_t stream) {
  const float* X    = (const float*)d_in[0];  // [B,L,D]
  const void*  mraw = d_in[1];                // [B,L] bool/int
  const float* W    = (const float*)d_in[2];  // [D,D]
  const float* bias = (const float*)d_in[3];  // [D]

  float* out   = (float*)d_out;
  float* align = out;                          // B*L*D fp32
  float* alpha = out + (size_t)B_ * L_ * D_;   // B*L*L fp32

  // Ph,Pl (bf16, 25.2MB each) live in the align region (dead until k_align).
  unsigned short* Ph = (unsigned short*)align;
  unsigned short* Pl = Ph + (size_t)B_ * L_ * D_;

  int* maskC = (int*)d_ws;                                          // 64 KB
  unsigned short* Xt = (unsigned short*)((char*)d_ws + 65536);      // 25.2 MB

  hipLaunchKernelGGL(k_mask, dim3(1), dim3(256), 0, stream, mraw, maskC);
  hipLaunchKernelGGL(k_proj, dim3(768), dim3(256), 0, stream, X, W, bias, Ph, Pl);
  hipLaunchKernelGGL(k_scores, dim3(576), dim3(256), 0, stream, Ph, Pl, maskC, alpha);
  hipLaunchKernelGGL(k_softmax, dim3(B_ * L_), dim3(256), 0, stream, alpha);
  hipLaunchKernelGGL(k_transpose, dim3(D_ / 32, L_ / 32, B_), dim3(256), 0, stream, X, Xt);
  hipLaunchKernelGGL(k_align, dim3(768), dim3(256), 0, stream, alpha, Xt, align);
}

// Round 5
// 303.135 us; speedup vs baseline: 3.2483x; 1.4001x over previous
//
#include <hip/hip_runtime.h>
#include <math.h>

// Problem constants
#define B_ 16
#define L_ 1024
#define D_ 768

typedef short bf16x8 __attribute__((ext_vector_type(8)));
typedef float f32x4 __attribute__((ext_vector_type(4)));

// round-to-nearest-even f32 -> bf16 (bit trick; inputs never NaN)
__device__ __forceinline__ unsigned short f2bf(float x) {
  unsigned u = __float_as_uint(x);
  u = (u + 0x7FFFu + ((u >> 16) & 1u)) >> 16;
  return (unsigned short)u;
}
__device__ __forceinline__ float bf2f(unsigned short h) {
  return __uint_as_float(((unsigned)h) << 16);
}

// ---------------------------------------------------------------------------
// K0: canonicalize mask (bool-bytes / int32 / int64 auto-detect). 1 = padding.
// ---------------------------------------------------------------------------
__global__ __launch_bounds__(256) void k_mask(const void* __restrict__ mraw,
                                              int* __restrict__ canon) {
  __shared__ int flags[2];
  if (threadIdx.x < 2) flags[threadIdx.x] = 0;
  __syncthreads();
  const unsigned* m32 = (const unsigned*)mraw;
  int gt = 0, oddnz = 0;
  for (int i = threadIdx.x; i < 4096; i += 256) {
    unsigned v = m32[i];
    if (v > 1u) gt = 1;
    if ((i & 1) && v != 0u) oddnz = 1;
  }
  if (gt) atomicOr(&flags[0], 1);
  if (oddnz) atomicOr(&flags[1], 1);
  __syncthreads();
  const int mode = flags[0] ? 0 : (flags[1] ? 1 : 2);  // 0=u8, 1=i32, 2=i64
  for (int i = threadIdx.x; i < B_ * L_; i += 256) {
    int v;
    if (mode == 0)      v = ((const unsigned char*)mraw)[i];
    else if (mode == 1) v = ((const int*)mraw)[i];
    else                v = (int)(((const long long*)mraw)[i] != 0);
    canon[i] = (v != 0);
  }
}

// ---------------------------------------------------------------------------
// K1 (MFMA): P = relu(X·W^T + b) -> bf16 hi/lo (Ph, Pl).  (unchanged r4)
// ---------------------------------------------------------------------------
__global__ __launch_bounds__(256) void k_proj(const float* __restrict__ X,
                                              const float* __restrict__ W,
                                              const float* __restrict__ bias,
                                              unsigned short* __restrict__ Ph,
                                              unsigned short* __restrict__ Pl) {
  __shared__ __align__(16) unsigned short smem[4 * 128 * 32];  // 32 KB
  unsigned short (*Ah)[32] = (unsigned short(*)[32])smem;
  unsigned short (*Al)[32] = (unsigned short(*)[32])(smem + 1 * 128 * 32);
  unsigned short (*Bh)[32] = (unsigned short(*)[32])(smem + 2 * 128 * 32);
  unsigned short (*Bl)[32] = (unsigned short(*)[32])(smem + 3 * 128 * 32);

  const int tid = threadIdx.x;
  const int swz = ((int)blockIdx.x % 8) * 96 + (int)blockIdx.x / 8;
  const int m0 = (swz / 6) * 128, n0 = (swz % 6) * 128;
  const int lane = tid & 63, wave = tid >> 6;
  const int wr = wave >> 1, wc = wave & 1;
  const int fr = lane & 15, kg = lane >> 4;
  f32x4 acc[4][4];
#pragma unroll
  for (int i = 0; i < 4; ++i)
#pragma unroll
    for (int j = 0; j < 4; ++j) acc[i][j] = 0;

  float4 av[4], bv[4];
#pragma unroll
  for (int p = 0; p < 4; ++p) {
    const int f = tid + p * 256, r = f >> 3, c = f & 7;
    av[p] = *(const float4*)(X + (size_t)(m0 + r) * D_ + c * 4);
    bv[p] = *(const float4*)(W + (size_t)(n0 + r) * D_ + c * 4);
  }

  for (int it = 0; it < D_ / 32; ++it) {
    __syncthreads();
#pragma unroll
    for (int p = 0; p < 4; ++p) {
      const int f = tid + p * 256, r = f >> 3, c = f & 7;
      {
        const float x0 = av[p].x, x1 = av[p].y, x2 = av[p].z, x3 = av[p].w;
        const unsigned short h0 = f2bf(x0), h1 = f2bf(x1), h2 = f2bf(x2), h3 = f2bf(x3);
        *(ushort4*)&Ah[r][c * 4] = make_ushort4(h0, h1, h2, h3);
        *(ushort4*)&Al[r][c * 4] = make_ushort4(f2bf(x0 - bf2f(h0)), f2bf(x1 - bf2f(h1)),
                                                f2bf(x2 - bf2f(h2)), f2bf(x3 - bf2f(h3)));
      }
      {
        const float x0 = bv[p].x, x1 = bv[p].y, x2 = bv[p].z, x3 = bv[p].w;
        const unsigned short h0 = f2bf(x0), h1 = f2bf(x1), h2 = f2bf(x2), h3 = f2bf(x3);
        *(ushort4*)&Bh[r][c * 4] = make_ushort4(h0, h1, h2, h3);
        *(ushort4*)&Bl[r][c * 4] = make_ushort4(f2bf(x0 - bf2f(h0)), f2bf(x1 - bf2f(h1)),
                                                f2bf(x2 - bf2f(h2)), f2bf(x3 - bf2f(h3)));
      }
    }
    __syncthreads();
    if (it + 1 < D_ / 32) {
      const int kk = (it + 1) * 32;
#pragma unroll
      for (int p = 0; p < 4; ++p) {
        const int f = tid + p * 256, r = f >> 3, c = f & 7;
        av[p] = *(const float4*)(X + (size_t)(m0 + r) * D_ + kk + c * 4);
        bv[p] = *(const float4*)(W + (size_t)(n0 + r) * D_ + kk + c * 4);
      }
    }
    bf16x8 fah[4], fal[4], fbh[4], fbl[4];
#pragma unroll
    for (int i = 0; i < 4; ++i) {
      fah[i] = *(const bf16x8*)&Ah[wr * 64 + i * 16 + fr][kg * 8];
      fal[i] = *(const bf16x8*)&Al[wr * 64 + i * 16 + fr][kg * 8];
      fbh[i] = *(const bf16x8*)&Bh[wc * 64 + i * 16 + fr][kg * 8];
      fbl[i] = *(const bf16x8*)&Bl[wc * 64 + i * 16 + fr][kg * 8];
    }
#pragma unroll
    for (int i = 0; i < 4; ++i)
#pragma unroll
      for (int j = 0; j < 4; ++j) {
        acc[i][j] = __builtin_amdgcn_mfma_f32_16x16x32_bf16(fah[i], fbh[j], acc[i][j], 0, 0, 0);
        acc[i][j] = __builtin_amdgcn_mfma_f32_16x16x32_bf16(fah[i], fbl[j], acc[i][j], 0, 0, 0);
        acc[i][j] = __builtin_amdgcn_mfma_f32_16x16x32_bf16(fal[i], fbh[j], acc[i][j], 0, 0, 0);
      }
  }

  unsigned short* scr = smem + wave * 2304;  // [2][16][72] ushort per wave
  const int row = lane >> 2, seg = lane & 3;
  float bj[4];
#pragma unroll
  for (int j = 0; j < 4; ++j) bj[j] = bias[n0 + wc * 64 + j * 16 + fr];
  for (int i = 0; i < 4; ++i) {
    __syncthreads();
#pragma unroll
    for (int j = 0; j < 4; ++j)
#pragma unroll
      for (int r = 0; r < 4; ++r) {
        float v = fmaxf(acc[i][j][r] + bj[j], 0.f);
        const unsigned short h = f2bf(v);
        scr[(kg * 4 + r) * 72 + j * 16 + fr] = h;
        scr[1152 + (kg * 4 + r) * 72 + j * 16 + fr] = f2bf(v - bf2f(h));
      }
    __syncthreads();
    const size_t gr = (size_t)(m0 + wr * 64 + i * 16 + row);
    const int gc0 = n0 + wc * 64 + seg * 16;
    const uint4 h0 = *(const uint4*)&scr[row * 72 + seg * 16];
    const uint4 h1 = *(const uint4*)&scr[row * 72 + seg * 16 + 8];
    const uint4 q0 = *(const uint4*)&scr[1152 + row * 72 + seg * 16];
    const uint4 q1 = *(const uint4*)&scr[1152 + row * 72 + seg * 16 + 8];
    *(uint4*)(Ph + gr * D_ + gc0)     = h0;
    *(uint4*)(Ph + gr * D_ + gc0 + 8) = h1;
    *(uint4*)(Pl + gr * D_ + gc0)     = q0;
    *(uint4*)(Pl + gr * D_ + gc0 + 8) = q1;
  }
}

// ---------------------------------------------------------------------------
// K2 (MFMA) v3: S = P·P^T, symmetric pairs, m97-style pipeline:
//  - global_load_lds dwordx4 staging (no VGPR round-trip),
//  - double-buffered LDS (2 x 32KB), one __syncthreads per K-step,
//  - combined hi|lo 128B LDS rows, XOR-swizzled via pre-swizzled global src,
//  - full-line coalesced main + LDS-staged mirror epilogues.
// LDS row layout (128B): 8 x 16B slots; LDS[row][s] = G[row][s ^ (row&7)]
// where G slots 0-3 = Ph 64B chunk, 4-7 = Pl 64B chunk of that K-tile.
// ---------------------------------------------------------------------------
__device__ __forceinline__ void stage_panel(const unsigned short* __restrict__ ph,
                                            const unsigned short* __restrict__ pl,
                                            size_t grow0, int kk,
                                            char* ldsbase, int wave, int lane) {
#pragma unroll
  for (int q = 0; q < 4; ++q) {
    const int s = wave * 4 + q;              // 1KB span: 8 rows x 128B
    const int row = s * 8 + (lane >> 3);
    const int xs = (lane & 7) ^ (row & 7);   // pre-swizzled source slot
    const unsigned short* src = (xs & 4) ? pl : ph;
    const unsigned short* g = src + (grow0 + row) * D_ + kk + (xs & 3) * 8;
    __builtin_amdgcn_global_load_lds(
        (const __attribute__((address_space(1))) void*)g,
        (__attribute__((address_space(3))) void*)(ldsbase + s * 1024),
        16, 0, 0);
  }
}

__device__ __forceinline__ bf16x8 ldsfrag(const char* base, int row, int g) {
  // g: 0-3 = hi slots, 4-7 = lo slots
  return *(const bf16x8*)(base + row * 128 + ((g ^ (row & 7)) * 16));
}

__global__ __launch_bounds__(256) void k_scores(const unsigned short* __restrict__ Ph,
                                                const unsigned short* __restrict__ Pl,
                                                const int* __restrict__ mask,
                                                float* __restrict__ S) {
  __shared__ __align__(16) char smem[65536];  // 2 buffers x (A 16KB + B 16KB)

  const int tid = threadIdx.x;
  const int swz = ((int)blockIdx.x % 8) * 72 + (int)blockIdx.x / 8;
  const int bb = swz / 36;
  const int pr = swz % 36;
  int ti = 0;
  while ((ti + 1) * (ti + 2) / 2 <= pr) ++ti;
  const int tj = pr - ti * (ti + 1) / 2;
  const int l0 = ti * 128, m0 = tj * 128;
  const int lane = tid & 63, wave = tid >> 6;
  const int wr = wave >> 1, wc = wave & 1;
  const int fr = lane & 15, kg = lane >> 4;
  f32x4 acc[4][4];
#pragma unroll
  for (int i = 0; i < 4; ++i)
#pragma unroll
    for (int j = 0; j < 4; ++j) acc[i][j] = 0;

  const size_t arow0 = (size_t)bb * L_ + l0;
  const size_t brow0 = (size_t)bb * L_ + m0;

  // prologue: stage K-tile 0 into buffer 0
  stage_panel(Ph, Pl, arow0, 0, smem, wave, lane);
  stage_panel(Ph, Pl, brow0, 0, smem + 16384, wave, lane);
  __syncthreads();  // drains vmcnt -> buffer 0 ready

  int cur = 0;
  for (int it = 0; it < D_ / 32; ++it) {
    char* cb = smem + cur * 32768;
    if (it + 1 < D_ / 32) {
      char* nb = smem + (cur ^ 1) * 32768;
      stage_panel(Ph, Pl, arow0, (it + 1) * 32, nb, wave, lane);
      stage_panel(Ph, Pl, brow0, (it + 1) * 32, nb + 16384, wave, lane);
    }
    bf16x8 fah[4], fal[4], fbh[4], fbl[4];
#pragma unroll
    for (int i = 0; i < 4; ++i) {
      const int ra = wr * 64 + i * 16 + fr;
      const int rb = wc * 64 + i * 16 + fr;
      fah[i] = ldsfrag(cb, ra, kg);
      fal[i] = ldsfrag(cb, ra, kg + 4);
      fbh[i] = ldsfrag(cb + 16384, rb, kg);
      fbl[i] = ldsfrag(cb + 16384, rb, kg + 4);
    }
#pragma unroll
    for (int i = 0; i < 4; ++i)
#pragma unroll
      for (int j = 0; j < 4; ++j) {
        acc[i][j] = __builtin_amdgcn_mfma_f32_16x16x32_bf16(fah[i], fbh[j], acc[i][j], 0, 0, 0);
        acc[i][j] = __builtin_amdgcn_mfma_f32_16x16x32_bf16(fah[i], fbl[j], acc[i][j], 0, 0, 0);
        acc[i][j] = __builtin_amdgcn_mfma_f32_16x16x32_bf16(fal[i], fbh[j], acc[i][j], 0, 0, 0);
      }
    __syncthreads();  // drains vmcnt (next buffer staged) + all reads of cb done
    cur ^= 1;
  }

  // ---- main tile epilogue: LDS transpose -> 64B/lane coalesced rows ----
  float* scr = (float*)smem + wave * 1280;
  const int row = lane >> 2, seg = lane & 3;
  for (int i = 0; i < 4; ++i) {
    __syncthreads();
#pragma unroll
    for (int j = 0; j < 4; ++j)
#pragma unroll
      for (int r = 0; r < 4; ++r)
        scr[(kg * 4 + r) * 68 + j * 16 + fr] = acc[i][j][r];
    __syncthreads();
    const int gl = l0 + wr * 64 + i * 16 + row;
    const int gm0 = m0 + wc * 64 + seg * 16;
    const size_t sbase = ((size_t)bb * L_ + gl) * L_ + gm0;
#pragma unroll
    for (int t = 0; t < 4; ++t) {
      float4 o = *(const float4*)&scr[row * 68 + seg * 16 + t * 4];
      const int4 mk = *(const int4*)(mask + bb * L_ + gm0 + t * 4);
      float* op = (float*)&o;
      const int* mp = (const int*)&mk;
#pragma unroll
      for (int e = 0; e < 4; ++e) {
        const int gm = gm0 + t * 4 + e;
        if (gm == gl) op[e] = 0.f;
        if (mp[e]) op[e] = -INFINITY;
      }
      *(float4*)(S + sbase + t * 4) = o;
    }
  }

  // ---- mirror tile: stage full 128x128 f32 transposed tile in LDS (64KB),
  //      then write full 512B-contiguous rows. col mask on gl. ----
  if (ti != tj) {
    __syncthreads();
#pragma unroll
    for (int j = 0; j < 4; ++j) {
      const int mloc = wc * 64 + j * 16 + fr;          // mirror row (m)
#pragma unroll
      for (int i = 0; i < 4; ++i) {
        const int slot = wr * 16 + i * 4 + kg;         // 16B col slot (l)
        const int xs = slot ^ (mloc & 7);
        *(f32x4*)(smem + mloc * 512 + xs * 16) = acc[i][j];
      }
    }
    __syncthreads();
    const int mrow = tid >> 1, half = tid & 1;
    const size_t sbase = ((size_t)bb * L_ + m0 + mrow) * L_ + l0;
#pragma unroll
    for (int q = 0; q < 16; ++q) {
      const int slot = half * 16 + q;
      const int xs = slot ^ (mrow & 7);
      float4 o = *(const float4*)(smem + mrow * 512 + xs * 16);
      const int4 mk = *(const int4*)(mask + bb * L_ + l0 + slot * 4);
      if (mk.x) o.x = -INFINITY;
      if (mk.y) o.y = -INFINITY;
      if (mk.z) o.z = -INFINITY;
      if (mk.w) o.w = -INFINITY;
      *(float4*)(S + sbase + slot * 4) = o;
    }
  }
}

// ---------------------------------------------------------------------------
// K3: in-place row softmax over 1024 keys.
// ---------------------------------------------------------------------------
__global__ __launch_bounds__(256) void k_softmax(float* __restrict__ S) {
  const size_t row = blockIdx.x;
  float4* rp = (float4*)(S + row * L_);
  float4 v = rp[threadIdx.x];
  float mx = fmaxf(fmaxf(v.x, v.y), fmaxf(v.z, v.w));
#pragma unroll
  for (int o = 32; o > 0; o >>= 1) mx = fmaxf(mx, __shfl_xor(mx, o));
  __shared__ float rmax[4], rsum[4];
  const int wv = threadIdx.x >> 6, ln = threadIdx.x & 63;
  if (ln == 0) rmax[wv] = mx;
  __syncthreads();
  mx = fmaxf(fmaxf(rmax[0], rmax[1]), fmaxf(rmax[2], rmax[3]));
  float4 e;
  e.x = __expf(v.x - mx); e.y = __expf(v.y - mx);
  e.z = __expf(v.z - mx); e.w = __expf(v.w - mx);
  float s = (e.x + e.y) + (e.z + e.w);
#pragma unroll
  for (int o = 32; o > 0; o >>= 1) s += __shfl_xor(s, o);
  if (ln == 0) rsum[wv] = s;
  __syncthreads();
  s = (rsum[0] + rsum[1]) + (rsum[2] + rsum[3]);
  const float inv = 1.0f / s;
  e.x *= inv; e.y *= inv; e.z *= inv; e.w *= inv;
  rp[threadIdx.x] = e;
}

// ---------------------------------------------------------------------------
// K4: Xt[b][d][m] = bf16(X[b][m][d])
// ---------------------------------------------------------------------------
__global__ __launch_bounds__(256) void k_transpose(const float* __restrict__ X,
                                                   unsigned short* __restrict__ Xt) {
  __shared__ float t[32][33];
  const int b = blockIdx.z;
  const int d0 = blockIdx.x * 32, m0 = blockIdx.y * 32;
  const int tx = threadIdx.x & 31, ty = threadIdx.x >> 5;
#pragma unroll
  for (int i = 0; i < 32; i += 8)
    t[ty + i][tx] = X[((size_t)b * L_ + m0 + ty + i) * D_ + d0 + tx];
  __syncthreads();
#pragma unroll
  for (int i = 0; i < 32; i += 8)
    Xt[((size_t)b * D_ + d0 + ty + i) * L_ + m0 + tx] = f2bf(t[tx][ty + i]);
}

// ---------------------------------------------------------------------------
// K5 (MFMA): align = alpha·X per batch.  (unchanged r4)
// ---------------------------------------------------------------------------
__global__ __launch_bounds__(256) void k_align(const float* __restrict__ A,
                                               const unsigned short* __restrict__ Xt,
                                               float* __restrict__ O) {
  __shared__ __align__(16) unsigned short smem[2 * 128 * 32];  // 16 KB staging
  __shared__ __align__(16) float scr_s[4 * 1104];              // 17.7 KB scratch
  unsigned short (*Ab)[32] = (unsigned short(*)[32])smem;
  unsigned short (*Bb)[32] = (unsigned short(*)[32])(smem + 128 * 32);

  const int tid = threadIdx.x;
  const int swz = ((int)blockIdx.x % 8) * 96 + (int)blockIdx.x / 8;
  const int bb = swz / 48;
  const int l0 = ((swz / 6) % 8) * 128;
  const int n0 = (swz % 6) * 128;
  const int lane = tid & 63, wave = tid >> 6;
  const int wr = wave >> 1, wc = wave & 1;
  const int fr = lane & 15, kg = lane >> 4;
  f32x4 acc[4][4];
#pragma unroll
  for (int i = 0; i < 4; ++i)
#pragma unroll
    for (int j = 0; j < 4; ++j) acc[i][j] = 0;

  float4 av[4];
  uint4 bv[2];
#pragma unroll
  for (int p = 0; p < 4; ++p) {
    const int f = tid + p * 256, r = f >> 3, c = f & 7;
    av[p] = *(const float4*)(A + ((size_t)bb * L_ + l0 + r) * L_ + c * 4);
  }
#pragma unroll
  for (int p = 0; p < 2; ++p) {
    const int f = tid + p * 256, r = f >> 2, sl = f & 3;
    bv[p] = *(const uint4*)(Xt + ((size_t)bb * D_ + n0 + r) * L_ + sl * 8);
  }

  for (int it = 0; it < L_ / 32; ++it) {
    __syncthreads();
#pragma unroll
    for (int p = 0; p < 4; ++p) {
      const int f = tid + p * 256, r = f >> 3, c = f & 7;
      *(ushort4*)&Ab[r][c * 4] = make_ushort4(f2bf(av[p].x), f2bf(av[p].y),
                                              f2bf(av[p].z), f2bf(av[p].w));
    }
#pragma unroll
    for (int p = 0; p < 2; ++p) {
      const int f = tid + p * 256, r = f >> 2, sl = f & 3;
      *(uint4*)&Bb[r][sl * 8] = bv[p];
    }
    __syncthreads();
    if (it + 1 < L_ / 32) {
      const int kk = (it + 1) * 32;
#pragma unroll
      for (int p = 0; p < 4; ++p) {
        const int f = tid + p * 256, r = f >> 3, c = f & 7;
        av[p] = *(const float4*)(A + ((size_t)bb * L_ + l0 + r) * L_ + kk + c * 4);
      }
#pragma unroll
      for (int p = 0; p < 2; ++p) {
        const int f = tid + p * 256, r = f >> 2, sl = f & 3;
        bv[p] = *(const uint4*)(Xt + ((size_t)bb * D_ + n0 + r) * L_ + kk + sl * 8);
      }
    }
    bf16x8 fa[4], fb[4];
#pragma unroll
    for (int i = 0; i < 4; ++i) {
      fa[i] = *(const bf16x8*)&Ab[wr * 64 + i * 16 + fr][kg * 8];
      fb[i] = *(const bf16x8*)&Bb[wc * 64 + i * 16 + fr][kg * 8];
    }
#pragma unroll
    for (int i = 0; i < 4; ++i)
#pragma unroll
      for (int j = 0; j < 4; ++j)
        acc[i][j] = __builtin_amdgcn_mfma_f32_16x16x32_bf16(fa[i], fb[j], acc[i][j], 0, 0, 0);
  }

  float* scr = scr_s + wave * 1104;
  const int row = lane >> 2, seg = lane & 3;
  for (int i = 0; i < 4; ++i) {
    __syncthreads();
#pragma unroll
    for (int j = 0; j < 4; ++j)
#pragma unroll
      for (int r = 0; r < 4; ++r)
        scr[(kg * 4 + r) * 68 + j * 16 + fr] = acc[i][j][r];
    __syncthreads();
    const int gl = l0 + wr * 64 + i * 16 + row;
    const int gc0 = n0 + wc * 64 + seg * 16;
    const size_t obase = ((size_t)bb * L_ + gl) * D_ + gc0;
#pragma unroll
    for (int t = 0; t < 4; ++t) {
      const float4 o = *(const float4*)&scr[row * 68 + seg * 16 + t * 4];
      *(float4*)(O + obase + t * 4) = o;
    }
  }
}

// ---------------------------------------------------------------------------
extern "C" void kernel_launch(void* const* d_in, const int* in_sizes, int n_in,
                              void* d_out, int out_size, void* d_ws, size_t ws_size,
                              hipStream_t stream) {
  const float* X    = (const float*)d_in[0];  // [B,L,D]
  const void*  mraw = d_in[1];                // [B,L] bool/int
  const float* W    = (const float*)d_in[2];  // [D,D]
  const float* bias = (const float*)d_in[3];  // [D]

  float* out   = (float*)d_out;
  float* align = out;                          // B*L*D fp32
  float* alpha = out + (size_t)B_ * L_ * D_;   // B*L*L fp32

  // Ph,Pl (bf16, 25.2MB each) live in the align region (dead until k_align).
  unsigned short* Ph = (unsigned short*)align;
  unsigned short* Pl = Ph + (size_t)B_ * L_ * D_;

  int* maskC = (int*)d_ws;                                          // 64 KB
  unsigned short* Xt = (unsigned short*)((char*)d_ws + 65536);      // 25.2 MB

  hipLaunchKernelGGL(k_mask, dim3(1), dim3(256), 0, stream, mraw, maskC);
  hipLaunchKernelGGL(k_proj, dim3(768), dim3(256), 0, stream, X, W, bias, Ph, Pl);
  hipLaunchKernelGGL(k_scores, dim3(576), dim3(256), 0, stream, Ph, Pl, maskC, alpha);
  hipLaunchKernelGGL(k_softmax, dim3(B_ * L_), dim3(256), 0, stream, alpha);
  hipLaunchKernelGGL(k_transpose, dim3(D_ / 32, L_ / 32, B_), dim3(256), 0, stream, X, Xt);
  hipLaunchKernelGGL(k_align, dim3(768), dim3(256), 0, stream, alpha, Xt, align);
}